// Round 1
// baseline (436.603 us; speedup 1.0000x reference)
//
#include <hip/hip_runtime.h>

typedef __attribute__((ext_vector_type(8))) short bf16x8;
typedef __attribute__((ext_vector_type(4))) float f32x4;

#define LOG2E 1.44269504088896f

__device__ __forceinline__ unsigned short f2bf(float f) {
  unsigned u = __builtin_bit_cast(unsigned, f);
  u += 0x7fffu + ((u >> 16) & 1u);
  return (unsigned short)(u >> 16);
}

__device__ __forceinline__ void gload16(const void* g, void* lds) {
  __builtin_amdgcn_global_load_lds(
      (const __attribute__((address_space(1))) void*)g,
      (__attribute__((address_space(3))) void*)lds, 16, 0, 0);
}

// ---------------- x -> bf16 ----------------
__global__ __launch_bounds__(256) void cvt_x(const float* __restrict__ in,
                                             unsigned short* __restrict__ out,
                                             int n4) {
  int i = blockIdx.x * 256 + threadIdx.x;
  int stride = gridDim.x * 256;
  for (; i < n4; i += stride) {
    float4 v = ((const float4*)in)[i];
    unsigned short o0 = f2bf(v.x), o1 = f2bf(v.y), o2 = f2bf(v.z), o3 = f2bf(v.w);
    unsigned long long packed = (unsigned long long)o0 | ((unsigned long long)o1 << 16) |
                                ((unsigned long long)o2 << 32) | ((unsigned long long)o3 << 48);
    ((unsigned long long*)out)[i] = packed;
  }
}

// ---------------- W[K][N] f32 -> WT[N][K] bf16 ----------------
__global__ __launch_bounds__(256) void transpose_w(const float* __restrict__ W,
                                                   unsigned short* __restrict__ WT) {
  __shared__ float tile[32][33];
  int bx = blockIdx.x, by = blockIdx.y;
  int x = bx * 32 + threadIdx.x;
  for (int i = 0; i < 4; ++i) {
    int r = threadIdx.y + i * 8;
    tile[r][threadIdx.x] = W[(by * 32 + r) * 1024 + x];
  }
  __syncthreads();
  int nx = by * 32 + threadIdx.x;
  for (int i = 0; i < 4; ++i) {
    int r = threadIdx.y + i * 8;
    WT[(long)(bx * 32 + r) * 1024 + nx] = f2bf(tile[threadIdx.x][r]);
  }
}

// ---------------- GEMM: C[M][N] = A[M][K] * BT[N][K]^T ----------------
template <int FP32OUT>
__global__ __launch_bounds__(256) void gemm_bt(const unsigned short* __restrict__ A,
                                               const unsigned short* __restrict__ BT,
                                               unsigned short* __restrict__ Cb,
                                               float* __restrict__ Cf,
                                               const float* __restrict__ bias,
                                               int M, int N, int K) {
  __shared__ alignas(16) unsigned short As[128 * 32];
  __shared__ alignas(16) unsigned short Bs[128 * 32];
  const int nbn = N >> 7;
  const int tm = blockIdx.x / nbn, tn = blockIdx.x % nbn;
  const int t = threadIdx.x, l = t & 63, w = t >> 6;
  const int wr = w >> 1, wc = w & 1;
  const int lr = l & 15, lg = l >> 4;

  f32x4 acc[4][4];
#pragma unroll
  for (int m = 0; m < 4; ++m)
#pragma unroll
    for (int n = 0; n < 4; ++n) acc[m][n] = f32x4{0.f, 0.f, 0.f, 0.f};

  const int srow = 16 * w + (l >> 2);   // 0..63
  const int scol = (l & 3) * 8;         // 0,8,16,24
  const unsigned short* Ab = A + (long)(tm * 128 + srow) * K + scol;
  const unsigned short* Bb = BT + (long)(tn * 128 + srow) * K + scol;
  unsigned short* AsW = As + w * 512;
  unsigned short* BsW = Bs + w * 512;

  for (int kt = 0; kt < K; kt += 32) {
    __syncthreads();
    gload16(Ab + kt, AsW);
    gload16(Ab + kt + 64 * (long)K, AsW + 2048);
    gload16(Bb + kt, BsW);
    gload16(Bb + kt + 64 * (long)K, BsW + 2048);
    __syncthreads();
    bf16x8 af[4], bfr[4];
#pragma unroll
    for (int m = 0; m < 4; ++m)
      af[m] = *(const bf16x8*)(As + (wr * 64 + m * 16 + lr) * 32 + lg * 8);
#pragma unroll
    for (int n = 0; n < 4; ++n)
      bfr[n] = *(const bf16x8*)(Bs + (wc * 64 + n * 16 + lr) * 32 + lg * 8);
#pragma unroll
    for (int m = 0; m < 4; ++m)
#pragma unroll
      for (int n = 0; n < 4; ++n)
        acc[m][n] = __builtin_amdgcn_mfma_f32_16x16x32_bf16(af[m], bfr[n], acc[m][n], 0, 0, 0);
  }

  const int crow = tm * 128 + wr * 64 + lg * 4;
  const int ccol = tn * 128 + wc * 64 + lr;
#pragma unroll
  for (int m = 0; m < 4; ++m)
#pragma unroll
    for (int n = 0; n < 4; ++n)
#pragma unroll
      for (int r = 0; r < 4; ++r) {
        long row = crow + m * 16 + r;
        int col = ccol + n * 16;
        if (FP32OUT)
          Cf[row * N + col] = acc[m][n][r] + bias[col];
        else
          Cb[row * N + col] = f2bf(acc[m][n][r]);
      }
}

// ---------------- Flash attention ----------------
// QKV: [8192][3072] bf16 (Q cols 0..1023, K 1024..2047, V 2048..3071)
// Ctx: [8192][1024] bf16
__global__ __launch_bounds__(256) void flash_attn(const unsigned short* __restrict__ QKV,
                                                  unsigned short* __restrict__ Ctx) {
  __shared__ alignas(16) unsigned short Ks[64 * 64];
  __shared__ alignas(16) unsigned short Vt[64 * 64];
  __shared__ alignas(16) unsigned short Ps[4][16 * 72];
  const int bid = blockIdx.x;
  const int qb = bid & 31, bh = bid >> 5;
  const int b = bh >> 4, h = bh & 15;
  const int t = threadIdx.x, l = t & 63, w = t >> 6;
  const int lr = l & 15, lg = l >> 4;
  const long rowbase = (long)b * 2048;
  const int colbase = h * 64;

  // Q fragments (A operand): lane lr = q-row, lg*8.. = k-chunk
  bf16x8 qf[2];
  {
    long qrow = rowbase + qb * 64 + w * 16 + lr;
#pragma unroll
    for (int kc = 0; kc < 2; ++kc)
      qf[kc] = *(const bf16x8*)(QKV + qrow * 3072 + colbase + kc * 32 + lg * 8);
  }

  f32x4 cacc[4];
  float m_r[4], l_r[4];
#pragma unroll
  for (int r = 0; r < 4; ++r) { m_r[r] = -1e30f; l_r[r] = 0.f; }
#pragma unroll
  for (int n = 0; n < 4; ++n) cacc[n] = f32x4{0.f, 0.f, 0.f, 0.f};

  // K staging geometry (global_load_lds, source pre-swizzled: phys hd' = hd ^ ((key&7)<<3))
  const int krow0 = 8 * w + (l >> 3);                 // + 32*i
  const int khd = ((l & 7) * 8) ^ ((l >> 3) << 3);    // swizzled source hd base
  // V staging geometry (register transpose into Vt[hd][key ^ (hd&56)])
  const int vkey0 = (t >> 3);                         // + 32*i
  const int vhd0 = (t & 7) * 8;

  for (int j = 0; j <= qb; ++j) {
    const int kv0 = j * 64;
    __syncthreads();
#pragma unroll
    for (int i = 0; i < 2; ++i)
      gload16(QKV + (rowbase + kv0 + krow0 + 32 * i) * 3072 + 1024 + colbase + khd,
              Ks + w * 512 + i * 2048);
#pragma unroll
    for (int i = 0; i < 2; ++i) {
      int key = vkey0 + 32 * i;
      bf16x8 vv = *(const bf16x8*)(QKV + (rowbase + kv0 + key) * 3072 + 2048 + colbase + vhd0);
#pragma unroll
      for (int jj = 0; jj < 8; ++jj)
        Vt[(vhd0 + jj) * 64 + (key ^ vhd0)] = (unsigned short)vv[jj];
    }
    __syncthreads();

    // scores: S = Q Kt  (16 q-rows x 64 keys per wave)
    float sc[4][4];
#pragma unroll
    for (int g = 0; g < 4; ++g) {
      const int key = g * 16 + lr;
      const int swz = (key & 7) << 3;
      bf16x8 k0 = *(const bf16x8*)(Ks + key * 64 + ((lg * 8) ^ swz));
      bf16x8 k1 = *(const bf16x8*)(Ks + key * 64 + ((32 + lg * 8) ^ swz));
      f32x4 z = f32x4{0.f, 0.f, 0.f, 0.f};
      z = __builtin_amdgcn_mfma_f32_16x16x32_bf16(qf[0], k0, z, 0, 0, 0);
      z = __builtin_amdgcn_mfma_f32_16x16x32_bf16(qf[1], k1, z, 0, 0, 0);
#pragma unroll
      for (int r = 0; r < 4; ++r) sc[g][r] = z[r] * 0.125f;
    }

    if (j == qb) {
#pragma unroll
      for (int g = 0; g < 4; ++g)
#pragma unroll
        for (int r = 0; r < 4; ++r)
          if (g * 16 + lr > w * 16 + lg * 4 + r) sc[g][r] = -1e30f;
    }

    // online softmax (rows live on 16-lane groups; lane-group lg owns rows lg*4..lg*4+3)
#pragma unroll
    for (int r = 0; r < 4; ++r) {
      float mx = fmaxf(fmaxf(sc[0][r], sc[1][r]), fmaxf(sc[2][r], sc[3][r]));
#pragma unroll
      for (int off = 1; off < 16; off <<= 1) mx = fmaxf(mx, __shfl_xor(mx, off));
      float mn = fmaxf(m_r[r], mx);
      float al = exp2f((m_r[r] - mn) * LOG2E);
      float rs = 0.f;
#pragma unroll
      for (int g = 0; g < 4; ++g) {
        float pv = exp2f((sc[g][r] - mn) * LOG2E);
        sc[g][r] = pv;
        rs += pv;
      }
#pragma unroll
      for (int off = 1; off < 16; off <<= 1) rs += __shfl_xor(rs, off);
      l_r[r] = l_r[r] * al + rs;
      m_r[r] = mn;
#pragma unroll
      for (int n = 0; n < 4; ++n) cacc[n][r] *= al;
    }

    // P -> per-wave LDS (relayout C/D -> A fragment)
#pragma unroll
    for (int g = 0; g < 4; ++g)
#pragma unroll
      for (int r = 0; r < 4; ++r)
        Ps[w][(lg * 4 + r) * 72 + g * 16 + lr] = f2bf(sc[g][r]);

    bf16x8 pa0 = *(const bf16x8*)(&Ps[w][lr * 72 + lg * 8]);
    bf16x8 pa1 = *(const bf16x8*)(&Ps[w][lr * 72 + 32 + lg * 8]);
#pragma unroll
    for (int n = 0; n < 4; ++n) {
      const int hd = n * 16 + lr;
      const int vswz = hd & 56;
      bf16x8 v0 = *(const bf16x8*)(Vt + hd * 64 + ((lg * 8) ^ vswz));
      bf16x8 v1 = *(const bf16x8*)(Vt + hd * 64 + ((32 + lg * 8) ^ vswz));
      cacc[n] = __builtin_amdgcn_mfma_f32_16x16x32_bf16(pa0, v0, cacc[n], 0, 0, 0);
      cacc[n] = __builtin_amdgcn_mfma_f32_16x16x32_bf16(pa1, v1, cacc[n], 0, 0, 0);
    }
  }

  // epilogue: Ctx = cacc / l
#pragma unroll
  for (int r = 0; r < 4; ++r) {
    float inv = 1.f / l_r[r];
    long row = rowbase + qb * 64 + w * 16 + lg * 4 + r;
#pragma unroll
    for (int n = 0; n < 4; ++n)
      Ctx[row * 1024 + colbase + n * 16 + lr] = f2bf(cacc[n][r] * inv);
  }
}

extern "C" void kernel_launch(void* const* d_in, const int* in_sizes, int n_in,
                              void* d_out, int out_size, void* d_ws, size_t ws_size,
                              hipStream_t stream) {
  (void)in_sizes; (void)n_in; (void)out_size; (void)ws_size;
  const float* x  = (const float*)d_in[0];
  const float* Wq = (const float*)d_in[1];
  const float* Wk = (const float*)d_in[2];
  const float* Wv = (const float*)d_in[3];
  const float* Wo = (const float*)d_in[4];
  const float* bo = (const float*)d_in[5];
  float* out = (float*)d_out;

  unsigned short* ws = (unsigned short*)d_ws;
  unsigned short* xb  = ws;                       // 8192*1024
  unsigned short* WqT = ws + 8388608;             // 1024*1024 (WqT,WkT,WvT contiguous)
  unsigned short* WkT = WqT + 1048576;
  unsigned short* WvT = WkT + 1048576;
  unsigned short* WoT = WvT + 1048576;
  unsigned short* QKV = WoT + 1048576;            // 8192*3072
  unsigned short* Ctx = QKV + 25165824;           // 8192*1024

  cvt_x<<<2048, 256, 0, stream>>>(x, xb, 8192 * 1024 / 4);

  dim3 tb(32, 8), tg(32, 32);
  transpose_w<<<tg, tb, 0, stream>>>(Wq, WqT);
  transpose_w<<<tg, tb, 0, stream>>>(Wk, WkT);
  transpose_w<<<tg, tb, 0, stream>>>(Wv, WvT);
  transpose_w<<<tg, tb, 0, stream>>>(Wo, WoT);

  // fused QKV projection: M=8192, N=3072, K=1024
  gemm_bt<0><<<64 * 24, 256, 0, stream>>>(xb, WqT, QKV, nullptr, nullptr, 8192, 3072, 1024);

  // flash attention: B*H=64 head-batches x 32 q-blocks
  flash_attn<<<2048, 256, 0, stream>>>(QKV, Ctx);

  // output projection + bias: fp32 out
  gemm_bt<1><<<64 * 8, 256, 0, stream>>>(Ctx, WoT, nullptr, out, bo, 8192, 1024, 1024);
}

// Round 2
// 229.318 us; speedup vs baseline: 1.9039x; 1.9039x over previous
//
#include <hip/hip_runtime.h>

typedef __attribute__((ext_vector_type(8))) short bf16x8;
typedef __attribute__((ext_vector_type(4))) float f32x4;
typedef __attribute__((ext_vector_type(4))) unsigned uint4v;

#define LOG2E 1.44269504088896f

__device__ __forceinline__ unsigned short f2bf(float f) {
  unsigned u = __builtin_bit_cast(unsigned, f);
  u += 0x7fffu + ((u >> 16) & 1u);
  return (unsigned short)(u >> 16);
}

__device__ __forceinline__ unsigned cvtpk(float lo, float hi) {
  unsigned r;
  asm volatile("v_cvt_pk_bf16_f32 %0, %1, %2" : "=v"(r) : "v"(lo), "v"(hi));
  return r;
}

__device__ __forceinline__ void gload16(const void* g, void* lds) {
  __builtin_amdgcn_global_load_lds(
      (const __attribute__((address_space(1))) void*)g,
      (__attribute__((address_space(3))) void*)lds, 16, 0, 0);
}

// ---------------- x -> bf16 ----------------
__global__ __launch_bounds__(256) void cvt_x(const float* __restrict__ in,
                                             unsigned short* __restrict__ out,
                                             int n4) {
  int i = blockIdx.x * 256 + threadIdx.x;
  int stride = gridDim.x * 256;
  for (; i < n4; i += stride) {
    float4 v = ((const float4*)in)[i];
    unsigned short o0 = f2bf(v.x), o1 = f2bf(v.y), o2 = f2bf(v.z), o3 = f2bf(v.w);
    unsigned long long packed = (unsigned long long)o0 | ((unsigned long long)o1 << 16) |
                                ((unsigned long long)o2 << 32) | ((unsigned long long)o3 << 48);
    ((unsigned long long*)out)[i] = packed;
  }
}

// ---------------- W[K][N] f32 -> WT[N][K] bf16 ----------------
__global__ __launch_bounds__(256) void transpose_w(const float* __restrict__ W,
                                                   unsigned short* __restrict__ WT) {
  __shared__ float tile[32][33];
  int bx = blockIdx.x, by = blockIdx.y;
  int x = bx * 32 + threadIdx.x;
  for (int i = 0; i < 4; ++i) {
    int r = threadIdx.y + i * 8;
    tile[r][threadIdx.x] = W[(by * 32 + r) * 1024 + x];
  }
  __syncthreads();
  int nx = by * 32 + threadIdx.x;
  for (int i = 0; i < 4; ++i) {
    int r = threadIdx.y + i * 8;
    WT[(long)(bx * 32 + r) * 1024 + nx] = f2bf(tile[threadIdx.x][r]);
  }
}

// ---------------- V columns of QKV -> Vt[bh][hd][s] ----------------
__global__ __launch_bounds__(256) void transpose_v(const unsigned short* __restrict__ QKV,
                                                   unsigned short* __restrict__ Vt) {
  __shared__ alignas(16) unsigned short tile[64][74];
  const int bid = blockIdx.x;
  const int st = bid & 31, bh = bid >> 5;
  const int b = bh >> 4, h = bh & 15;
  const int t = threadIdx.x;
  const int r = t >> 2, c16 = (t & 3) * 16;
  const unsigned short* src =
      QKV + ((long)(b * 2048 + st * 64 + r)) * 3072 + 2048 + h * 64 + c16;
  uint4v v0 = *(const uint4v*)src;
  uint4v v1 = *(const uint4v*)(src + 8);
  unsigned* dst32 = (unsigned*)&tile[r][c16];
  dst32[0] = v0[0]; dst32[1] = v0[1]; dst32[2] = v0[2]; dst32[3] = v0[3];
  dst32[4] = v1[0]; dst32[5] = v1[1]; dst32[6] = v1[2]; dst32[7] = v1[3];
  __syncthreads();
  const int lw = t & 63, w = t >> 6;
#pragma unroll
  for (int k = 0; k < 16; ++k) {
    int hd = w * 16 + k;
    Vt[((long)(bh * 64 + hd)) * 2048 + st * 64 + lw] = tile[lw][hd];
  }
}

// ---------------- GEMM: C[M][N] = A[M][K] * BT[N][K]^T ----------------
template <int FP32OUT>
__global__ __launch_bounds__(256) void gemm_bt(const unsigned short* __restrict__ A,
                                               const unsigned short* __restrict__ BT,
                                               unsigned short* __restrict__ Cb,
                                               float* __restrict__ Cf,
                                               const float* __restrict__ bias,
                                               int M, int N, int K) {
  __shared__ alignas(16) unsigned short As[128 * 32];
  __shared__ alignas(16) unsigned short Bs[128 * 32];
  const int nbn = N >> 7;
  const int tm = blockIdx.x / nbn, tn = blockIdx.x % nbn;
  const int t = threadIdx.x, l = t & 63, w = t >> 6;
  const int wr = w >> 1, wc = w & 1;
  const int lr = l & 15, lg = l >> 4;

  f32x4 acc[4][4];
#pragma unroll
  for (int m = 0; m < 4; ++m)
#pragma unroll
    for (int n = 0; n < 4; ++n) acc[m][n] = f32x4{0.f, 0.f, 0.f, 0.f};

  const int srow = 16 * w + (l >> 2);
  const int scol = (l & 3) * 8;
  const unsigned short* Ab = A + (long)(tm * 128 + srow) * K + scol;
  const unsigned short* Bb = BT + (long)(tn * 128 + srow) * K + scol;
  unsigned short* AsW = As + w * 512;
  unsigned short* BsW = Bs + w * 512;

  for (int kt = 0; kt < K; kt += 32) {
    __syncthreads();
    gload16(Ab + kt, AsW);
    gload16(Ab + kt + 64 * (long)K, AsW + 2048);
    gload16(Bb + kt, BsW);
    gload16(Bb + kt + 64 * (long)K, BsW + 2048);
    __syncthreads();
    bf16x8 af[4], bfr[4];
#pragma unroll
    for (int m = 0; m < 4; ++m)
      af[m] = *(const bf16x8*)(As + (wr * 64 + m * 16 + lr) * 32 + lg * 8);
#pragma unroll
    for (int n = 0; n < 4; ++n)
      bfr[n] = *(const bf16x8*)(Bs + (wc * 64 + n * 16 + lr) * 32 + lg * 8);
#pragma unroll
    for (int m = 0; m < 4; ++m)
#pragma unroll
      for (int n = 0; n < 4; ++n)
        acc[m][n] = __builtin_amdgcn_mfma_f32_16x16x32_bf16(af[m], bfr[n], acc[m][n], 0, 0, 0);
  }

  const int crow = tm * 128 + wr * 64 + lg * 4;
  const int ccol = tn * 128 + wc * 64 + lr;
#pragma unroll
  for (int m = 0; m < 4; ++m)
#pragma unroll
    for (int n = 0; n < 4; ++n)
#pragma unroll
      for (int r = 0; r < 4; ++r) {
        long row = crow + m * 16 + r;
        int col = ccol + n * 16;
        if (FP32OUT)
          Cf[row * N + col] = acc[m][n][r] + bias[col];
        else
          Cb[row * N + col] = f2bf(acc[m][n][r]);
      }
}

// ---------------- Flash attention (swapped QK^T, in-register softmax) -------
// QKV: [8192][3072] bf16 (Q 0..1023, K 1024..2047, V 2048..3071)
// Vt : [64 bh][64 hd][2048 s] bf16  (V transposed)
// Ctx: [8192][1024] bf16
__global__ __launch_bounds__(256) void flash_attn(const unsigned short* __restrict__ QKV,
                                                  const unsigned short* __restrict__ Vt,
                                                  unsigned short* __restrict__ Ctx) {
  __shared__ alignas(16) unsigned short Ks[2][64 * 64];  // [key][hd^swz(key)]
  __shared__ alignas(16) unsigned short Vs[2][64 * 64];  // [hd][key^swz(hd)]
  const int bid = blockIdx.x;
  const int qt = 15 - (bid >> 6);  // heavy q-tiles dispatched first
  const int bh = bid & 63;
  const int b = bh >> 4, h = bh & 15;
  const int t = threadIdx.x, l = t & 63, w = t >> 6;
  const int lr = l & 15, lg = l >> 4;
  const long rowbase = (long)b * 2048;
  const int colbase = h * 64;
  const int qbase = qt * 128 + w * 32;

  // Q fragments (B operand of swapped QK^T): Q[q=rg*16+lr][hd=c*32+lg*8+j]
  bf16x8 qf[2][2];
#pragma unroll
  for (int rg = 0; rg < 2; ++rg)
#pragma unroll
    for (int c = 0; c < 2; ++c)
      qf[rg][c] = *(const bf16x8*)(QKV + (rowbase + qbase + rg * 16 + lr) * 3072 +
                                   colbase + c * 32 + lg * 8);

  f32x4 cacc[2][4];
  float m_r[2], l_r[2];
#pragma unroll
  for (int rg = 0; rg < 2; ++rg) {
    m_r[rg] = -1e30f;
    l_r[rg] = 0.f;
#pragma unroll
    for (int n = 0; n < 4; ++n) cacc[rg][n] = f32x4{0.f, 0.f, 0.f, 0.f};
  }

  const int srow = w * 16 + (l >> 3);  // + 8*i
  const int scol = (l & 7) * 8;
  const int nkv = 2 * qt + 2;

#define STAGE(buf, j)                                                                   \
  do {                                                                                  \
    const int kv0_ = (j) * 64;                                                          \
    _Pragma("unroll") for (int i_ = 0; i_ < 2; ++i_) {                                  \
      int kr_ = srow + 8 * i_;                                                          \
      gload16(QKV + (rowbase + kv0_ + kr_) * 3072 + 1024 + colbase +                    \
                  (scol ^ ((kr_ & 7) << 3)),                                            \
              &Ks[buf][(w * 16 + 8 * i_) * 64]);                                        \
    }                                                                                   \
    _Pragma("unroll") for (int i_ = 0; i_ < 2; ++i_) {                                  \
      int vr_ = srow + 8 * i_;                                                          \
      gload16(Vt + ((long)(bh * 64 + vr_)) * 2048 + kv0_ + (scol ^ ((vr_ & 7) << 3)),   \
              &Vs[buf][(w * 16 + 8 * i_) * 64]);                                        \
    }                                                                                   \
  } while (0)

  STAGE(0, 0);
  __syncthreads();

  for (int j = 0; j < nkv; ++j) {
    const int cur = j & 1;
    if (j + 1 < nkv) STAGE(cur ^ 1, j + 1);
    const int kv0 = j * 64;
    const unsigned short* Kc = Ks[cur];
    const unsigned short* Vc = Vs[cur];

    // QK^T (swapped): p[rg][g] = S[key=kv0+g*16+lg*4+reg][q=qbase+rg*16+lr]
    f32x4 p[2][4];
#pragma unroll
    for (int rg = 0; rg < 2; ++rg)
#pragma unroll
      for (int g = 0; g < 4; ++g) p[rg][g] = f32x4{0.f, 0.f, 0.f, 0.f};
#pragma unroll
    for (int g = 0; g < 4; ++g) {
      const int key = g * 16 + lr;
      const int swz = (key & 7) << 3;
#pragma unroll
      for (int c = 0; c < 2; ++c) {
        bf16x8 kf = *(const bf16x8*)(Kc + key * 64 + ((c * 32 + lg * 8) ^ swz));
        p[0][g] = __builtin_amdgcn_mfma_f32_16x16x32_bf16(kf, qf[0][c], p[0][g], 0, 0, 0);
        p[1][g] = __builtin_amdgcn_mfma_f32_16x16x32_bf16(kf, qf[1][c], p[1][g], 0, 0, 0);
      }
    }

    // scale + causal mask (last two tiles only)
    const bool domask = (j >= nkv - 2);
#pragma unroll
    for (int rg = 0; rg < 2; ++rg) {
      const int qrow = qbase + rg * 16 + lr;
#pragma unroll
      for (int g = 0; g < 4; ++g)
#pragma unroll
        for (int r = 0; r < 4; ++r) {
          float s = p[rg][g][r] * 0.125f;
          if (domask && (kv0 + g * 16 + lg * 4 + r > qrow)) s = -1e30f;
          p[rg][g][r] = s;
        }
    }

    // online softmax: row q=lr lives across lanes {lr, lr+16, lr+32, lr+48}
    unsigned pk[2][4][2];
#pragma unroll
    for (int rg = 0; rg < 2; ++rg) {
      float mloc = -1e30f;
#pragma unroll
      for (int g = 0; g < 4; ++g)
#pragma unroll
        for (int r = 0; r < 4; ++r) mloc = fmaxf(mloc, p[rg][g][r]);
      mloc = fmaxf(mloc, __shfl_xor(mloc, 16));
      mloc = fmaxf(mloc, __shfl_xor(mloc, 32));
      float mn = fmaxf(m_r[rg], mloc);
      float alpha = exp2f((m_r[rg] - mn) * LOG2E);
      float rs = 0.f;
#pragma unroll
      for (int g = 0; g < 4; ++g)
#pragma unroll
        for (int r = 0; r < 4; ++r) {
          float e = exp2f((p[rg][g][r] - mn) * LOG2E);
          p[rg][g][r] = e;
          rs += e;
        }
      rs += __shfl_xor(rs, 16);
      rs += __shfl_xor(rs, 32);
      l_r[rg] = l_r[rg] * alpha + rs;
      m_r[rg] = mn;
      // redistribute alpha to accumulator layout (acc row q' = lg*4+r)
      float alq[4];
#pragma unroll
      for (int r = 0; r < 4; ++r) alq[r] = __shfl(alpha, lg * 20 + r);
#pragma unroll
      for (int n = 0; n < 4; ++n)
#pragma unroll
        for (int r = 0; r < 4; ++r) cacc[rg][n][r] *= alq[r];
      // pack P to bf16 pairs
#pragma unroll
      for (int g = 0; g < 4; ++g) {
        pk[rg][g][0] = cvtpk(p[rg][g][0], p[rg][g][1]);
        pk[rg][g][1] = cvtpk(p[rg][g][2], p[rg][g][3]);
      }
    }

    // PV: rebuild A-fragments in-register via shuffles, MFMA against V^T
    const bool hi = (lg >> 1) != 0;
    const int srcA = lr + 32 * (lg & 1), srcB = srcA + 16;
#pragma unroll
    for (int s = 0; s < 2; ++s) {
      bf16x8 vf[4];
#pragma unroll
      for (int n = 0; n < 4; ++n) {
        const int hd = n * 16 + lr;
        vf[n] = *(const bf16x8*)(Vc + hd * 64 + ((s * 32 + lg * 8) ^ ((hd & 7) << 3)));
      }
#pragma unroll
      for (int rg = 0; rg < 2; ++rg) {
        unsigned a0 = __shfl(pk[rg][2 * s][0], srcA);
        unsigned a1 = __shfl(pk[rg][2 * s + 1][0], srcA);
        unsigned w0v = hi ? a1 : a0;
        unsigned b0 = __shfl(pk[rg][2 * s][1], srcA);
        unsigned b1 = __shfl(pk[rg][2 * s + 1][1], srcA);
        unsigned w1v = hi ? b1 : b0;
        unsigned c0 = __shfl(pk[rg][2 * s][0], srcB);
        unsigned c1 = __shfl(pk[rg][2 * s + 1][0], srcB);
        unsigned w2v = hi ? c1 : c0;
        unsigned d0 = __shfl(pk[rg][2 * s][1], srcB);
        unsigned d1 = __shfl(pk[rg][2 * s + 1][1], srcB);
        unsigned w3v = hi ? d1 : d0;
        uint4v pw = {w0v, w1v, w2v, w3v};
        bf16x8 pa = __builtin_bit_cast(bf16x8, pw);
#pragma unroll
        for (int n = 0; n < 4; ++n)
          cacc[rg][n] = __builtin_amdgcn_mfma_f32_16x16x32_bf16(pa, vf[n], cacc[rg][n], 0, 0, 0);
      }
    }
    __syncthreads();
  }

  // epilogue: Ctx = cacc / l  (acc row q' = lg*4+r, col hd = n*16+lr)
#pragma unroll
  for (int rg = 0; rg < 2; ++rg) {
    float invl = 1.f / l_r[rg];
    float ilq[4];
#pragma unroll
    for (int r = 0; r < 4; ++r) ilq[r] = __shfl(invl, lg * 20 + r);
#pragma unroll
    for (int n = 0; n < 4; ++n)
#pragma unroll
      for (int r = 0; r < 4; ++r) {
        long row = rowbase + qbase + rg * 16 + lg * 4 + r;
        Ctx[row * 1024 + colbase + n * 16 + lr] = f2bf(cacc[rg][n][r] * ilq[r]);
      }
  }
#undef STAGE
}

extern "C" void kernel_launch(void* const* d_in, const int* in_sizes, int n_in,
                              void* d_out, int out_size, void* d_ws, size_t ws_size,
                              hipStream_t stream) {
  (void)in_sizes; (void)n_in; (void)out_size; (void)ws_size;
  const float* x  = (const float*)d_in[0];
  const float* Wq = (const float*)d_in[1];
  const float* Wk = (const float*)d_in[2];
  const float* Wv = (const float*)d_in[3];
  const float* Wo = (const float*)d_in[4];
  const float* bo = (const float*)d_in[5];
  float* out = (float*)d_out;

  unsigned short* ws = (unsigned short*)d_ws;
  unsigned short* xb  = ws;                       // 8192*1024 (dead after QKV GEMM)
  unsigned short* Vt  = ws;                       // aliases xb: written after GEMM
  unsigned short* WqT = ws + 8388608;
  unsigned short* WkT = WqT + 1048576;
  unsigned short* WvT = WkT + 1048576;
  unsigned short* WoT = WvT + 1048576;
  unsigned short* QKV = WoT + 1048576;            // 8192*3072
  unsigned short* Ctx = QKV + 25165824;           // 8192*1024

  cvt_x<<<2048, 256, 0, stream>>>(x, xb, 8192 * 1024 / 4);

  dim3 tb(32, 8), tg(32, 32);
  transpose_w<<<tg, tb, 0, stream>>>(Wq, WqT);
  transpose_w<<<tg, tb, 0, stream>>>(Wk, WkT);
  transpose_w<<<tg, tb, 0, stream>>>(Wv, WvT);
  transpose_w<<<tg, tb, 0, stream>>>(Wo, WoT);

  // fused QKV projection: M=8192, N=3072, K=1024
  gemm_bt<0><<<64 * 24, 256, 0, stream>>>(xb, WqT, QKV, nullptr, nullptr, 8192, 3072, 1024);

  // V -> Vt[bh][hd][s]  (xb is dead now; Vt aliases it)
  transpose_v<<<2048, 256, 0, stream>>>(QKV, Vt);

  // flash attention: 64 bh x 16 q-tiles of 128 rows
  flash_attn<<<1024, 256, 0, stream>>>(QKV, Vt, Ctx);

  // output projection + bias: fp32 out
  gemm_bt<1><<<64 * 8, 256, 0, stream>>>(Ctx, WoT, nullptr, out, bo, 8192, 1024, 1024);
}

// Round 3
// 205.680 us; speedup vs baseline: 2.1227x; 1.1149x over previous
//
#include <hip/hip_runtime.h>

typedef __attribute__((ext_vector_type(8))) short bf16x8;
typedef __attribute__((ext_vector_type(4))) float f32x4;
typedef __attribute__((ext_vector_type(4))) unsigned uint4v;

#define LOG2E 1.44269504088896f
#define SM_C 0.18033688011112042f  // 0.125 * log2(e)

__device__ __forceinline__ unsigned short f2bf(float f) {
  unsigned u = __builtin_bit_cast(unsigned, f);
  u += 0x7fffu + ((u >> 16) & 1u);
  return (unsigned short)(u >> 16);
}

__device__ __forceinline__ unsigned cvtpk(float lo, float hi) {
  unsigned r;
  asm volatile("v_cvt_pk_bf16_f32 %0, %1, %2" : "=v"(r) : "v"(lo), "v"(hi));
  return r;
}

__device__ __forceinline__ void gload16(const void* g, void* lds) {
  __builtin_amdgcn_global_load_lds(
      (const __attribute__((address_space(1))) void*)g,
      (__attribute__((address_space(3))) void*)lds, 16, 0, 0);
}

// ---------------- x -> bf16 ----------------
__global__ __launch_bounds__(256) void cvt_x(const float* __restrict__ in,
                                             unsigned short* __restrict__ out,
                                             int n4) {
  int i = blockIdx.x * 256 + threadIdx.x;
  int stride = gridDim.x * 256;
  for (; i < n4; i += stride) {
    float4 v = ((const float4*)in)[i];
    unsigned short o0 = f2bf(v.x), o1 = f2bf(v.y), o2 = f2bf(v.z), o3 = f2bf(v.w);
    unsigned long long packed = (unsigned long long)o0 | ((unsigned long long)o1 << 16) |
                                ((unsigned long long)o2 << 32) | ((unsigned long long)o3 << 48);
    ((unsigned long long*)out)[i] = packed;
  }
}

// ---------------- W[K][N] f32 -> WT[N][K] bf16 ----------------
__global__ __launch_bounds__(256) void transpose_w(const float* __restrict__ W,
                                                   unsigned short* __restrict__ WT) {
  __shared__ float tile[32][33];
  int bx = blockIdx.x, by = blockIdx.y;
  int x = bx * 32 + threadIdx.x;
  for (int i = 0; i < 4; ++i) {
    int r = threadIdx.y + i * 8;
    tile[r][threadIdx.x] = W[(by * 32 + r) * 1024 + x];
  }
  __syncthreads();
  int nx = by * 32 + threadIdx.x;
  for (int i = 0; i < 4; ++i) {
    int r = threadIdx.y + i * 8;
    WT[(long)(bx * 32 + r) * 1024 + nx] = f2bf(tile[threadIdx.x][r]);
  }
}

// ---------------- V columns of QKV -> Vt[bh][hd][s_perm] ----------------
// Key permutation: physical p = s*32+g01*16+lg*4+r  ->  virtual v = s*32+lg*8+g01*4+r
// so the PV A-fragment in flash_attn needs NO cross-lane shuffles.
__global__ __launch_bounds__(256) void transpose_v(const unsigned short* __restrict__ QKV,
                                                   unsigned short* __restrict__ Vt) {
  __shared__ alignas(16) unsigned short tile[64][74];
  const int bid = blockIdx.x;
  const int st = bid & 31, bh = bid >> 5;
  const int b = bh >> 4, h = bh & 15;
  const int t = threadIdx.x;
  const int r = t >> 2, c16 = (t & 3) * 16;
  const unsigned short* src =
      QKV + ((long)(b * 2048 + st * 64 + r)) * 3072 + 2048 + h * 64 + c16;
  uint4v v0 = *(const uint4v*)src;
  uint4v v1 = *(const uint4v*)(src + 8);
  unsigned* dst32 = (unsigned*)&tile[r][c16];
  dst32[0] = v0[0]; dst32[1] = v0[1]; dst32[2] = v0[2]; dst32[3] = v0[3];
  dst32[4] = v1[0]; dst32[5] = v1[1]; dst32[6] = v1[2]; dst32[7] = v1[3];
  __syncthreads();
  const int lw = t & 63, w = t >> 6;
  const int vp = (lw & 32) | (((lw >> 2) & 3) << 3) | (((lw >> 4) & 1) << 2) | (lw & 3);
#pragma unroll
  for (int k = 0; k < 16; ++k) {
    int hd = w * 16 + k;
    Vt[((long)(bh * 64 + hd)) * 2048 + st * 64 + vp] = tile[lw][hd];
  }
}

// ---------------- GEMM: C[M][N] = A[M][K] * BT[N][K]^T ----------------
template <int FP32OUT>
__global__ __launch_bounds__(256) void gemm_bt(const unsigned short* __restrict__ A,
                                               const unsigned short* __restrict__ BT,
                                               unsigned short* __restrict__ Cb,
                                               float* __restrict__ Cf,
                                               const float* __restrict__ bias,
                                               int M, int N, int K) {
  __shared__ alignas(16) unsigned short As[128 * 32];
  __shared__ alignas(16) unsigned short Bs[128 * 32];
  const int nbn = N >> 7;
  const int tm = blockIdx.x / nbn, tn = blockIdx.x % nbn;
  const int t = threadIdx.x, l = t & 63, w = t >> 6;
  const int wr = w >> 1, wc = w & 1;
  const int lr = l & 15, lg = l >> 4;

  f32x4 acc[4][4];
#pragma unroll
  for (int m = 0; m < 4; ++m)
#pragma unroll
    for (int n = 0; n < 4; ++n) acc[m][n] = f32x4{0.f, 0.f, 0.f, 0.f};

  const int srow = 16 * w + (l >> 2);
  const int scol = (l & 3) * 8;
  const unsigned short* Ab = A + (long)(tm * 128 + srow) * K + scol;
  const unsigned short* Bb = BT + (long)(tn * 128 + srow) * K + scol;
  unsigned short* AsW = As + w * 512;
  unsigned short* BsW = Bs + w * 512;

  for (int kt = 0; kt < K; kt += 32) {
    __syncthreads();
    gload16(Ab + kt, AsW);
    gload16(Ab + kt + 64 * (long)K, AsW + 2048);
    gload16(Bb + kt, BsW);
    gload16(Bb + kt + 64 * (long)K, BsW + 2048);
    __syncthreads();
    bf16x8 af[4], bfr[4];
#pragma unroll
    for (int m = 0; m < 4; ++m)
      af[m] = *(const bf16x8*)(As + (wr * 64 + m * 16 + lr) * 32 + lg * 8);
#pragma unroll
    for (int n = 0; n < 4; ++n)
      bfr[n] = *(const bf16x8*)(Bs + (wc * 64 + n * 16 + lr) * 32 + lg * 8);
#pragma unroll
    for (int m = 0; m < 4; ++m)
#pragma unroll
      for (int n = 0; n < 4; ++n)
        acc[m][n] = __builtin_amdgcn_mfma_f32_16x16x32_bf16(af[m], bfr[n], acc[m][n], 0, 0, 0);
  }

  const int crow = tm * 128 + wr * 64 + lg * 4;
  const int ccol = tn * 128 + wc * 64 + lr;
#pragma unroll
  for (int m = 0; m < 4; ++m)
#pragma unroll
    for (int n = 0; n < 4; ++n)
#pragma unroll
      for (int r = 0; r < 4; ++r) {
        long row = crow + m * 16 + r;
        int col = ccol + n * 16;
        if (FP32OUT)
          Cf[row * N + col] = acc[m][n][r] + bias[col];
        else
          Cb[row * N + col] = f2bf(acc[m][n][r]);
      }
}

// ---------------- Flash attention (swapped QK^T, zero-shuffle PV) -----------
__global__ __launch_bounds__(256) void flash_attn(const unsigned short* __restrict__ QKV,
                                                  const unsigned short* __restrict__ Vt,
                                                  unsigned short* __restrict__ Ctx) {
  __shared__ alignas(16) unsigned short Ks[2][64 * 64];  // [key][hd^swz(key)]
  __shared__ alignas(16) unsigned short Vs[2][64 * 64];  // [hd][vkey^swz(hd)]
  const int bid = blockIdx.x;
  // per-CU load balance: each CU's 4 resident chunks get qt's summing to 30
  const int ci = bid >> 6;
  const int kk = ci >> 2, rr = ci & 3;
  const int qt = 4 * kk + ((kk & 1) ? 3 - rr : rr);
  const int bh = bid & 63;
  const int b = bh >> 4, h = bh & 15;
  const int t = threadIdx.x, l = t & 63, w = t >> 6;
  const int lr = l & 15, lg = l >> 4;
  const long rowbase = (long)b * 2048;
  const int colbase = h * 64;
  const int qbase = qt * 128 + w * 32;

  // Q fragments (B operand of swapped QK^T)
  bf16x8 qf[2][2];
#pragma unroll
  for (int rg = 0; rg < 2; ++rg)
#pragma unroll
    for (int c = 0; c < 2; ++c)
      qf[rg][c] = *(const bf16x8*)(QKV + (rowbase + qbase + rg * 16 + lr) * 3072 +
                                   colbase + c * 32 + lg * 8);

  f32x4 cacc[2][4];
  float m_r[2], l_r[2];
#pragma unroll
  for (int rg = 0; rg < 2; ++rg) {
    m_r[rg] = -1e30f;
    l_r[rg] = 0.f;
#pragma unroll
    for (int n = 0; n < 4; ++n) cacc[rg][n] = f32x4{0.f, 0.f, 0.f, 0.f};
  }

  const int srow = w * 16 + (l >> 3);
  const int scol = (l & 7) * 8;
  const int nkv = 2 * qt + 2;

#define STAGE(buf, j)                                                                   \
  do {                                                                                  \
    const int kv0_ = (j) * 64;                                                          \
    _Pragma("unroll") for (int i_ = 0; i_ < 2; ++i_) {                                  \
      int kr_ = srow + 8 * i_;                                                          \
      gload16(QKV + (rowbase + kv0_ + kr_) * 3072 + 1024 + colbase +                    \
                  (scol ^ ((kr_ & 7) << 3)),                                            \
              &Ks[buf][(w * 16 + 8 * i_) * 64]);                                        \
    }                                                                                   \
    _Pragma("unroll") for (int i_ = 0; i_ < 2; ++i_) {                                  \
      int vr_ = srow + 8 * i_;                                                          \
      gload16(Vt + ((long)(bh * 64 + vr_)) * 2048 + kv0_ + (scol ^ ((vr_ & 7) << 3)),   \
              &Vs[buf][(w * 16 + 8 * i_) * 64]);                                        \
    }                                                                                   \
  } while (0)

  STAGE(0, 0);
  __syncthreads();

  for (int j = 0; j < nkv; ++j) {
    const int cur = j & 1;
    if (j + 1 < nkv) STAGE(cur ^ 1, j + 1);
    const int kv0 = j * 64;
    const unsigned short* Kc = Ks[cur];
    const unsigned short* Vc = Vs[cur];

    // QK^T (swapped): p[rg][g] = S[key=kv0+g*16+lg*4+reg][q=qbase+rg*16+lr]  (raw)
    f32x4 p[2][4];
#pragma unroll
    for (int rg = 0; rg < 2; ++rg)
#pragma unroll
      for (int g = 0; g < 4; ++g) p[rg][g] = f32x4{0.f, 0.f, 0.f, 0.f};
    __builtin_amdgcn_s_setprio(1);
#pragma unroll
    for (int g = 0; g < 4; ++g) {
      const int key = g * 16 + lr;
      const int swz = (key & 7) << 3;
#pragma unroll
      for (int c = 0; c < 2; ++c) {
        bf16x8 kf = *(const bf16x8*)(Kc + key * 64 + ((c * 32 + lg * 8) ^ swz));
        p[0][g] = __builtin_amdgcn_mfma_f32_16x16x32_bf16(kf, qf[0][c], p[0][g], 0, 0, 0);
        p[1][g] = __builtin_amdgcn_mfma_f32_16x16x32_bf16(kf, qf[1][c], p[1][g], 0, 0, 0);
      }
    }
    __builtin_amdgcn_s_setprio(0);

    // causal mask on raw scores (last two tiles only)
    if (j >= nkv - 2) {
#pragma unroll
      for (int rg = 0; rg < 2; ++rg) {
        const int qrow = qbase + rg * 16 + lr;
#pragma unroll
        for (int g = 0; g < 4; ++g)
#pragma unroll
          for (int r = 0; r < 4; ++r)
            if (kv0 + g * 16 + lg * 4 + r > qrow) p[rg][g][r] = -1e30f;
      }
    }

    // online softmax in raw domain; e = exp2(fma(p, C, -m*C))
    unsigned pk[2][4][2];
#pragma unroll
    for (int rg = 0; rg < 2; ++rg) {
      float mloc = p[rg][0][0];
#pragma unroll
      for (int g = 0; g < 4; ++g)
#pragma unroll
        for (int r = 0; r < 4; ++r) mloc = fmaxf(mloc, p[rg][g][r]);
      mloc = fmaxf(mloc, __shfl_xor(mloc, 16));
      mloc = fmaxf(mloc, __shfl_xor(mloc, 32));
      const bool defer = __all(mloc <= m_r[rg] + 44.0f);
      const float mn = defer ? m_r[rg] : fmaxf(m_r[rg], mloc);
      const float nmc = -mn * SM_C;
      float rs = 0.f;
#pragma unroll
      for (int g = 0; g < 4; ++g)
#pragma unroll
        for (int r = 0; r < 4; ++r) {
          float e = __builtin_amdgcn_exp2f(__builtin_fmaf(p[rg][g][r], SM_C, nmc));
          p[rg][g][r] = e;
          rs += e;
        }
      rs += __shfl_xor(rs, 16);
      rs += __shfl_xor(rs, 32);
      if (defer) {
        l_r[rg] += rs;
      } else {
        float alpha = __builtin_amdgcn_exp2f((m_r[rg] - mn) * SM_C);
        l_r[rg] = l_r[rg] * alpha + rs;
        m_r[rg] = mn;
        float alq[4];
#pragma unroll
        for (int r = 0; r < 4; ++r) alq[r] = __shfl(alpha, lg * 20 + r);
#pragma unroll
        for (int n = 0; n < 4; ++n)
#pragma unroll
          for (int r = 0; r < 4; ++r) cacc[rg][n][r] *= alq[r];
      }
#pragma unroll
      for (int g = 0; g < 4; ++g) {
        pk[rg][g][0] = cvtpk(p[rg][g][0], p[rg][g][1]);
        pk[rg][g][1] = cvtpk(p[rg][g][2], p[rg][g][3]);
      }
    }

    // PV: A-fragment is the lane's own registers (key permutation in Vt)
#pragma unroll
    for (int s = 0; s < 2; ++s) {
      bf16x8 vf[4];
#pragma unroll
      for (int n = 0; n < 4; ++n) {
        const int hd = n * 16 + lr;
        vf[n] = *(const bf16x8*)(Vc + hd * 64 + ((s * 32 + lg * 8) ^ ((hd & 7) << 3)));
      }
      __builtin_amdgcn_s_setprio(1);
#pragma unroll
      for (int rg = 0; rg < 2; ++rg) {
        uint4v pw = {pk[rg][2 * s][0], pk[rg][2 * s][1], pk[rg][2 * s + 1][0], pk[rg][2 * s + 1][1]};
        bf16x8 pa = __builtin_bit_cast(bf16x8, pw);
#pragma unroll
        for (int n = 0; n < 4; ++n)
          cacc[rg][n] = __builtin_amdgcn_mfma_f32_16x16x32_bf16(pa, vf[n], cacc[rg][n], 0, 0, 0);
      }
      __builtin_amdgcn_s_setprio(0);
    }
    __syncthreads();
  }

  // epilogue: Ctx = cacc / l  (acc row q' = lg*4+r, col hd = n*16+lr)
#pragma unroll
  for (int rg = 0; rg < 2; ++rg) {
    float invl = 1.f / l_r[rg];
    float ilq[4];
#pragma unroll
    for (int r = 0; r < 4; ++r) ilq[r] = __shfl(invl, lg * 20 + r);
#pragma unroll
    for (int n = 0; n < 4; ++n)
#pragma unroll
      for (int r = 0; r < 4; ++r) {
        long row = rowbase + qbase + rg * 16 + lg * 4 + r;
        Ctx[row * 1024 + colbase + n * 16 + lr] = f2bf(cacc[rg][n][r] * ilq[r]);
      }
  }
#undef STAGE
}

extern "C" void kernel_launch(void* const* d_in, const int* in_sizes, int n_in,
                              void* d_out, int out_size, void* d_ws, size_t ws_size,
                              hipStream_t stream) {
  (void)in_sizes; (void)n_in; (void)out_size; (void)ws_size;
  const float* x  = (const float*)d_in[0];
  const float* Wq = (const float*)d_in[1];
  const float* Wk = (const float*)d_in[2];
  const float* Wv = (const float*)d_in[3];
  const float* Wo = (const float*)d_in[4];
  const float* bo = (const float*)d_in[5];
  float* out = (float*)d_out;

  unsigned short* ws = (unsigned short*)d_ws;
  unsigned short* xb  = ws;                       // 8192*1024 (dead after QKV GEMM)
  unsigned short* Vt  = ws;                       // aliases xb: written after GEMM
  unsigned short* WqT = ws + 8388608;
  unsigned short* WkT = WqT + 1048576;
  unsigned short* WvT = WkT + 1048576;
  unsigned short* WoT = WvT + 1048576;
  unsigned short* QKV = WoT + 1048576;            // 8192*3072
  unsigned short* Ctx = QKV + 25165824;           // 8192*1024

  cvt_x<<<2048, 256, 0, stream>>>(x, xb, 8192 * 1024 / 4);

  dim3 tb(32, 8), tg(32, 32);
  transpose_w<<<tg, tb, 0, stream>>>(Wq, WqT);
  transpose_w<<<tg, tb, 0, stream>>>(Wk, WkT);
  transpose_w<<<tg, tb, 0, stream>>>(Wv, WvT);
  transpose_w<<<tg, tb, 0, stream>>>(Wo, WoT);

  // fused QKV projection: M=8192, N=3072, K=1024
  gemm_bt<0><<<64 * 24, 256, 0, stream>>>(xb, WqT, QKV, nullptr, nullptr, 8192, 3072, 1024);

  // V -> Vt[bh][hd][s_perm]  (xb is dead now; Vt aliases it)
  transpose_v<<<2048, 256, 0, stream>>>(QKV, Vt);

  // flash attention: 64 bh x 16 q-tiles of 128 rows
  flash_attn<<<1024, 256, 0, stream>>>(QKV, Vt, Ctx);

  // output projection + bias: fp32 out
  gemm_bt<1><<<64 * 8, 256, 0, stream>>>(Ctx, WoT, nullptr, out, bo, 8192, 1024, 1024);
}

// Round 4
// 187.338 us; speedup vs baseline: 2.3306x; 1.0979x over previous
//
#include <hip/hip_runtime.h>

typedef __attribute__((ext_vector_type(8))) short bf16x8;
typedef __attribute__((ext_vector_type(4))) float f32x4;
typedef __attribute__((ext_vector_type(4))) unsigned uint4v;

#define SM_C 0.18033688011112042f  // 0.125 * log2(e)
#define MFMA16 __builtin_amdgcn_mfma_f32_16x16x32_bf16

__device__ __forceinline__ unsigned short f2bf(float f) {
  unsigned u = __builtin_bit_cast(unsigned, f);
  u += 0x7fffu + ((u >> 16) & 1u);
  return (unsigned short)(u >> 16);
}

__device__ __forceinline__ unsigned cvtpk(float lo, float hi) {
  unsigned r;
  asm volatile("v_cvt_pk_bf16_f32 %0, %1, %2" : "=v"(r) : "v"(lo), "v"(hi));
  return r;
}

__device__ __forceinline__ void gload16(const void* g, void* lds) {
  __builtin_amdgcn_global_load_lds(
      (const __attribute__((address_space(1))) void*)g,
      (__attribute__((address_space(3))) void*)lds, 16, 0, 0);
}

// ---------------- x -> bf16 ----------------
__global__ __launch_bounds__(256) void cvt_x(const float* __restrict__ in,
                                             unsigned short* __restrict__ out,
                                             int n4) {
  int i = blockIdx.x * 256 + threadIdx.x;
  int stride = gridDim.x * 256;
  for (; i < n4; i += stride) {
    float4 v = ((const float4*)in)[i];
    unsigned short o0 = f2bf(v.x), o1 = f2bf(v.y), o2 = f2bf(v.z), o3 = f2bf(v.w);
    unsigned long long packed = (unsigned long long)o0 | ((unsigned long long)o1 << 16) |
                                ((unsigned long long)o2 << 32) | ((unsigned long long)o3 << 48);
    ((unsigned long long*)out)[i] = packed;
  }
}

// ---------------- W[K][N] f32 -> WT[N][K] bf16 ----------------
__global__ __launch_bounds__(256) void transpose_w(const float* __restrict__ W,
                                                   unsigned short* __restrict__ WT) {
  __shared__ float tile[32][33];
  int bx = blockIdx.x, by = blockIdx.y;
  int x = bx * 32 + threadIdx.x;
  for (int i = 0; i < 4; ++i) {
    int r = threadIdx.y + i * 8;
    tile[r][threadIdx.x] = W[(by * 32 + r) * 1024 + x];
  }
  __syncthreads();
  int nx = by * 32 + threadIdx.x;
  for (int i = 0; i < 4; ++i) {
    int r = threadIdx.y + i * 8;
    WT[(long)(bx * 32 + r) * 1024 + nx] = f2bf(tile[threadIdx.x][r]);
  }
}

// ---------------- V columns of QKV -> Vt[bh][hd][s_perm] ----------------
// Key permutation: physical p = s*32+g01*16+lg*4+r  ->  virtual v = s*32+lg*8+g01*4+r
// so the PV A-fragment in flash_attn needs NO cross-lane shuffles.
__global__ __launch_bounds__(256) void transpose_v(const unsigned short* __restrict__ QKV,
                                                   unsigned short* __restrict__ Vt) {
  __shared__ alignas(16) unsigned short tile[64][74];
  const int bid = blockIdx.x;
  const int st = bid & 31, bh = bid >> 5;
  const int b = bh >> 4, h = bh & 15;
  const int t = threadIdx.x;
  const int r = t >> 2, c16 = (t & 3) * 16;
  const unsigned short* src =
      QKV + ((long)(b * 2048 + st * 64 + r)) * 3072 + 2048 + h * 64 + c16;
  uint4v v0 = *(const uint4v*)src;
  uint4v v1 = *(const uint4v*)(src + 8);
  unsigned* dst32 = (unsigned*)&tile[r][c16];
  dst32[0] = v0[0]; dst32[1] = v0[1]; dst32[2] = v0[2]; dst32[3] = v0[3];
  dst32[4] = v1[0]; dst32[5] = v1[1]; dst32[6] = v1[2]; dst32[7] = v1[3];
  __syncthreads();
  const int lw = t & 63, w = t >> 6;
  const int vp = (lw & 32) | (((lw >> 2) & 3) << 3) | (((lw >> 4) & 1) << 2) | (lw & 3);
#pragma unroll
  for (int k = 0; k < 16; ++k) {
    int hd = w * 16 + k;
    Vt[((long)(bh * 64 + hd)) * 2048 + st * 64 + vp] = tile[lw][hd];
  }
}

// ---------------- GEMM: C[M][N] = A[M][K] * BT[N][K]^T ----------------
template <int FP32OUT>
__global__ __launch_bounds__(256) void gemm_bt(const unsigned short* __restrict__ A,
                                               const unsigned short* __restrict__ BT,
                                               unsigned short* __restrict__ Cb,
                                               float* __restrict__ Cf,
                                               const float* __restrict__ bias,
                                               int M, int N, int K) {
  __shared__ alignas(16) unsigned short As[128 * 32];
  __shared__ alignas(16) unsigned short Bs[128 * 32];
  const int nbn = N >> 7;
  const int tm = blockIdx.x / nbn, tn = blockIdx.x % nbn;
  const int t = threadIdx.x, l = t & 63, w = t >> 6;
  const int wr = w >> 1, wc = w & 1;
  const int lr = l & 15, lg = l >> 4;

  f32x4 acc[4][4];
#pragma unroll
  for (int m = 0; m < 4; ++m)
#pragma unroll
    for (int n = 0; n < 4; ++n) acc[m][n] = f32x4{0.f, 0.f, 0.f, 0.f};

  const int srow = 16 * w + (l >> 2);
  const int scol = (l & 3) * 8;
  const unsigned short* Ab = A + (long)(tm * 128 + srow) * K + scol;
  const unsigned short* Bb = BT + (long)(tn * 128 + srow) * K + scol;
  unsigned short* AsW = As + w * 512;
  unsigned short* BsW = Bs + w * 512;

  for (int kt = 0; kt < K; kt += 32) {
    __syncthreads();
    gload16(Ab + kt, AsW);
    gload16(Ab + kt + 64 * (long)K, AsW + 2048);
    gload16(Bb + kt, BsW);
    gload16(Bb + kt + 64 * (long)K, BsW + 2048);
    __syncthreads();
    bf16x8 af[4], bfr[4];
#pragma unroll
    for (int m = 0; m < 4; ++m)
      af[m] = *(const bf16x8*)(As + (wr * 64 + m * 16 + lr) * 32 + lg * 8);
#pragma unroll
    for (int n = 0; n < 4; ++n)
      bfr[n] = *(const bf16x8*)(Bs + (wc * 64 + n * 16 + lr) * 32 + lg * 8);
#pragma unroll
    for (int m = 0; m < 4; ++m)
#pragma unroll
      for (int n = 0; n < 4; ++n)
        acc[m][n] = MFMA16(af[m], bfr[n], acc[m][n], 0, 0, 0);
  }

  const int crow = tm * 128 + wr * 64 + lg * 4;
  const int ccol = tn * 128 + wc * 64 + lr;
#pragma unroll
  for (int m = 0; m < 4; ++m)
#pragma unroll
    for (int n = 0; n < 4; ++n)
#pragma unroll
      for (int r = 0; r < 4; ++r) {
        long row = crow + m * 16 + r;
        int col = ccol + n * 16;
        if (FP32OUT)
          Cf[row * N + col] = acc[m][n][r] + bias[col];
        else
          Cb[row * N + col] = f2bf(acc[m][n][r]);
      }
}

// ---------------- Flash attention tile body ----------------
// TWO=1: both strips active; TWO=0: only strip 1 (the long strip).
template <int TWO>
__device__ __forceinline__ void attn_tile(
    const unsigned short* __restrict__ Kc, const unsigned short* __restrict__ Vc,
    int lr, int lg, bool mask0, bool mask1, int kv0, int q0row, int q1row,
    const bf16x8 (&qf)[2][2], f32x4 (&cacc)[2][4], float (&m_r)[2], float (&l_r)[2]) {
  constexpr int S0 = TWO ? 0 : 1;
  f32x4 p[2][4];
#pragma unroll
  for (int s = S0; s < 2; ++s)
#pragma unroll
    for (int g = 0; g < 4; ++g) p[s][g] = f32x4{0.f, 0.f, 0.f, 0.f};

  // QK^T (swapped): p[s][g][r] = S[key=kv0+g*16+lg*4+r][q = qsrow + lr]
  __builtin_amdgcn_s_setprio(1);
#pragma unroll
  for (int g = 0; g < 4; ++g) {
    const int key = g * 16 + lr;
    const int swz = (key & 7) << 3;
#pragma unroll
    for (int c = 0; c < 2; ++c) {
      bf16x8 kf = *(const bf16x8*)(Kc + key * 64 + ((c * 32 + lg * 8) ^ swz));
#pragma unroll
      for (int s = S0; s < 2; ++s)
        p[s][g] = MFMA16(kf, qf[s][c], p[s][g], 0, 0, 0);
    }
  }
  __builtin_amdgcn_s_setprio(0);

  if (TWO && mask0) {
#pragma unroll
    for (int g = 0; g < 4; ++g)
#pragma unroll
      for (int r = 0; r < 4; ++r)
        if (kv0 + g * 16 + lg * 4 + r > q0row) p[0][g][r] = -1e30f;
  }
  if (mask1) {
#pragma unroll
    for (int g = 0; g < 4; ++g)
#pragma unroll
      for (int r = 0; r < 4; ++r)
        if (kv0 + g * 16 + lg * 4 + r > q1row) p[1][g][r] = -1e30f;
  }

  // online softmax (raw domain), defer-max
  unsigned pk[2][4][2];
#pragma unroll
  for (int s = S0; s < 2; ++s) {
    float mloc = p[s][0][0];
#pragma unroll
    for (int g = 0; g < 4; ++g)
#pragma unroll
      for (int r = 0; r < 4; ++r) mloc = fmaxf(mloc, p[s][g][r]);
    mloc = fmaxf(mloc, __shfl_xor(mloc, 16));
    mloc = fmaxf(mloc, __shfl_xor(mloc, 32));
    const bool defer = __all(mloc <= m_r[s] + 44.0f);
    const float mn = defer ? m_r[s] : fmaxf(m_r[s], mloc);
    const float nmc = -mn * SM_C;
    float rs = 0.f;
#pragma unroll
    for (int g = 0; g < 4; ++g)
#pragma unroll
      for (int r = 0; r < 4; ++r) {
        float e = __builtin_amdgcn_exp2f(__builtin_fmaf(p[s][g][r], SM_C, nmc));
        p[s][g][r] = e;
        rs += e;
      }
    rs += __shfl_xor(rs, 16);
    rs += __shfl_xor(rs, 32);
    if (defer) {
      l_r[s] += rs;
    } else {
      float alpha = __builtin_amdgcn_exp2f((m_r[s] - mn) * SM_C);
      l_r[s] = l_r[s] * alpha + rs;
      m_r[s] = mn;
      float alq[4];
#pragma unroll
      for (int r = 0; r < 4; ++r) alq[r] = __shfl(alpha, lg * 20 + r);
#pragma unroll
      for (int n = 0; n < 4; ++n)
#pragma unroll
        for (int r = 0; r < 4; ++r) cacc[s][n][r] *= alq[r];
    }
#pragma unroll
    for (int g = 0; g < 4; ++g) {
      pk[s][g][0] = cvtpk(p[s][g][0], p[s][g][1]);
      pk[s][g][1] = cvtpk(p[s][g][2], p[s][g][3]);
    }
  }

  // PV: A-fragment is the lane's own registers (key permutation in Vt)
#pragma unroll
  for (int sl = 0; sl < 2; ++sl) {
    bf16x8 vf[4];
#pragma unroll
    for (int n = 0; n < 4; ++n) {
      const int hd = n * 16 + lr;
      vf[n] = *(const bf16x8*)(Vc + hd * 64 + ((sl * 32 + lg * 8) ^ ((hd & 7) << 3)));
    }
    __builtin_amdgcn_s_setprio(1);
#pragma unroll
    for (int s = S0; s < 2; ++s) {
      uint4v pw = {pk[s][2 * sl][0], pk[s][2 * sl][1], pk[s][2 * sl + 1][0], pk[s][2 * sl + 1][1]};
      bf16x8 pa = __builtin_bit_cast(bf16x8, pw);
#pragma unroll
      for (int n = 0; n < 4; ++n)
        cacc[s][n] = MFMA16(pa, vf[n], cacc[s][n], 0, 0, 0);
    }
    __builtin_amdgcn_s_setprio(0);
  }
}

// ---------------- Flash attention (paired causal strips) ----------------
// Block (qt, bh): strips q in [qt*64, qt*64+64) and [(31-qt)*64, (31-qt)*64+64),
// one shared K/V stream j=0..31-qt. Uniform 33 strip-tile units per block.
__global__ __launch_bounds__(256, 4) void flash_attn(const unsigned short* __restrict__ QKV,
                                                     const unsigned short* __restrict__ Vt,
                                                     unsigned short* __restrict__ Ctx) {
  __shared__ alignas(16) unsigned short Ks[2][64 * 64];  // [key][hd^swz(key)]
  __shared__ alignas(16) unsigned short Vs[2][64 * 64];  // [hd][vkey^swz(hd)]
  const int bid = blockIdx.x;
  const int qt = bid >> 6;  // 0..15
  const int bh = bid & 63;
  const int b = bh >> 4, h = bh & 15;
  const int t = threadIdx.x, l = t & 63, w = t >> 6;
  const int lr = l & 15, lg = l >> 4;
  const long rowbase = (long)b * 2048;
  const int colbase = h * 64;
  const int q0 = qt * 64 + w * 16;         // short strip
  const int q1 = (31 - qt) * 64 + w * 16;  // long strip
  const int q0row = q0 + lr, q1row = q1 + lr;
  const int nkv = 32 - qt;

  // Q fragments (B operand of swapped QK^T)
  bf16x8 qf[2][2];
#pragma unroll
  for (int c = 0; c < 2; ++c) {
    qf[0][c] = *(const bf16x8*)(QKV + (rowbase + q0 + lr) * 3072 + colbase + c * 32 + lg * 8);
    qf[1][c] = *(const bf16x8*)(QKV + (rowbase + q1 + lr) * 3072 + colbase + c * 32 + lg * 8);
  }

  f32x4 cacc[2][4];
  float m_r[2], l_r[2];
#pragma unroll
  for (int s = 0; s < 2; ++s) {
    m_r[s] = -1e30f;
    l_r[s] = 0.f;
#pragma unroll
    for (int n = 0; n < 4; ++n) cacc[s][n] = f32x4{0.f, 0.f, 0.f, 0.f};
  }

  // staging pointers (source pre-swizzled; LDS dest linear — rule 21)
  const int srow = w * 16 + (l >> 3);
  const int scol = (l & 7) * 8;
  const int kswz = scol ^ ((srow & 7) << 3);
  const unsigned short* kp = QKV + (rowbase + srow) * 3072 + 1024 + colbase + kswz;
  const unsigned short* vp = Vt + ((long)(bh * 64 + srow)) * 2048 + kswz;
  unsigned short* ksd0 = &Ks[0][(w * 16) * 64];
  unsigned short* vsd0 = &Vs[0][(w * 16) * 64];

#define STAGE(buf)                                    \
  do {                                                \
    gload16(kp, ksd0 + (buf) * 4096);                 \
    gload16(kp + 8 * 3072, ksd0 + (buf) * 4096 + 512);\
    gload16(vp, vsd0 + (buf) * 4096);                 \
    gload16(vp + 8 * 2048, vsd0 + (buf) * 4096 + 512);\
    kp += 64 * 3072;                                  \
    vp += 64;                                         \
  } while (0)

  STAGE(0);
  __syncthreads();

  int j = 0;
  for (; j <= qt; ++j) {  // both strips active
    const int cur = j & 1;
    if (j + 1 < nkv) STAGE(cur ^ 1);
    attn_tile<1>(Ks[cur], Vs[cur], lr, lg, j == qt, false, j * 64, q0row, q1row,
                 qf, cacc, m_r, l_r);
    __syncthreads();
  }
  for (; j < nkv; ++j) {  // long strip only
    const int cur = j & 1;
    if (j + 1 < nkv) STAGE(cur ^ 1);
    attn_tile<0>(Ks[cur], Vs[cur], lr, lg, false, j == nkv - 1, j * 64, q0row, q1row,
                 qf, cacc, m_r, l_r);
    __syncthreads();
  }
#undef STAGE

  // epilogue: Ctx = cacc / l  (acc row q' = lg*4+r, col hd = n*16+lr)
#pragma unroll
  for (int s = 0; s < 2; ++s) {
    float invl = 1.f / l_r[s];
    float ilq[4];
#pragma unroll
    for (int r = 0; r < 4; ++r) ilq[r] = __shfl(invl, lg * 20 + r);
    const int qs = (s == 0) ? q0 : q1;
#pragma unroll
    for (int n = 0; n < 4; ++n)
#pragma unroll
      for (int r = 0; r < 4; ++r) {
        long row = rowbase + qs + lg * 4 + r;
        Ctx[row * 1024 + colbase + n * 16 + lr] = f2bf(cacc[s][n][r] * ilq[r]);
      }
  }
}

extern "C" void kernel_launch(void* const* d_in, const int* in_sizes, int n_in,
                              void* d_out, int out_size, void* d_ws, size_t ws_size,
                              hipStream_t stream) {
  (void)in_sizes; (void)n_in; (void)out_size; (void)ws_size;
  const float* x  = (const float*)d_in[0];
  const float* Wq = (const float*)d_in[1];
  const float* Wk = (const float*)d_in[2];
  const float* Wv = (const float*)d_in[3];
  const float* Wo = (const float*)d_in[4];
  const float* bo = (const float*)d_in[5];
  float* out = (float*)d_out;

  unsigned short* ws = (unsigned short*)d_ws;
  unsigned short* xb  = ws;                       // 8192*1024 (dead after QKV GEMM)
  unsigned short* Vt  = ws;                       // aliases xb: written after GEMM
  unsigned short* WqT = ws + 8388608;
  unsigned short* WkT = WqT + 1048576;
  unsigned short* WvT = WkT + 1048576;
  unsigned short* WoT = WvT + 1048576;
  unsigned short* QKV = WoT + 1048576;            // 8192*3072
  unsigned short* Ctx = QKV + 25165824;           // 8192*1024

  cvt_x<<<2048, 256, 0, stream>>>(x, xb, 8192 * 1024 / 4);

  dim3 tb(32, 8), tg(32, 32);
  transpose_w<<<tg, tb, 0, stream>>>(Wq, WqT);
  transpose_w<<<tg, tb, 0, stream>>>(Wk, WkT);
  transpose_w<<<tg, tb, 0, stream>>>(Wv, WvT);
  transpose_w<<<tg, tb, 0, stream>>>(Wo, WoT);

  // fused QKV projection: M=8192, N=3072, K=1024
  gemm_bt<0><<<64 * 24, 256, 0, stream>>>(xb, WqT, QKV, nullptr, nullptr, 8192, 3072, 1024);

  // V -> Vt[bh][hd][s_perm]  (xb is dead now; Vt aliases it)
  transpose_v<<<2048, 256, 0, stream>>>(QKV, Vt);

  // flash attention: 64 bh x 16 paired-strip blocks (uniform duration)
  flash_attn<<<1024, 256, 0, stream>>>(QKV, Vt, Ctx);

  // output projection + bias: fp32 out
  gemm_bt<1><<<64 * 8, 256, 0, stream>>>(Ctx, WoT, nullptr, out, bo, 8192, 1024, 1024);
}

// Round 5
// 176.117 us; speedup vs baseline: 2.4791x; 1.0637x over previous
//
#include <hip/hip_runtime.h>

typedef __attribute__((ext_vector_type(8))) short bf16x8;
typedef __attribute__((ext_vector_type(4))) float f32x4;
typedef __attribute__((ext_vector_type(4))) unsigned uint4v;

#define SM_C 0.18033688011112042f  // 0.125 * log2(e)
#define MFMA16 __builtin_amdgcn_mfma_f32_16x16x32_bf16

__device__ __forceinline__ unsigned short f2bf(float f) {
  unsigned u = __builtin_bit_cast(unsigned, f);
  u += 0x7fffu + ((u >> 16) & 1u);
  return (unsigned short)(u >> 16);
}

__device__ __forceinline__ unsigned cvtpk(float lo, float hi) {
  unsigned r;
  asm volatile("v_cvt_pk_bf16_f32 %0, %1, %2" : "=v"(r) : "v"(lo), "v"(hi));
  return r;
}

__device__ __forceinline__ void gload16(const void* g, void* lds) {
  __builtin_amdgcn_global_load_lds(
      (const __attribute__((address_space(1))) void*)g,
      (__attribute__((address_space(3))) void*)lds, 16, 0, 0);
}

// ---------------- x -> bf16 ----------------
__global__ __launch_bounds__(256) void cvt_x(const float* __restrict__ in,
                                             unsigned short* __restrict__ out,
                                             int n4) {
  int i = blockIdx.x * 256 + threadIdx.x;
  int stride = gridDim.x * 256;
  for (; i < n4; i += stride) {
    float4 v = ((const float4*)in)[i];
    unsigned short o0 = f2bf(v.x), o1 = f2bf(v.y), o2 = f2bf(v.z), o3 = f2bf(v.w);
    unsigned long long packed = (unsigned long long)o0 | ((unsigned long long)o1 << 16) |
                                ((unsigned long long)o2 << 32) | ((unsigned long long)o3 << 48);
    ((unsigned long long*)out)[i] = packed;
  }
}

// ---------------- W[K][N] f32 -> WT[N][K] bf16 ----------------
__global__ __launch_bounds__(256) void transpose_w(const float* __restrict__ W,
                                                   unsigned short* __restrict__ WT) {
  __shared__ float tile[32][33];
  int bx = blockIdx.x, by = blockIdx.y;
  int x = bx * 32 + threadIdx.x;
  for (int i = 0; i < 4; ++i) {
    int r = threadIdx.y + i * 8;
    tile[r][threadIdx.x] = W[(by * 32 + r) * 1024 + x];
  }
  __syncthreads();
  int nx = by * 32 + threadIdx.x;
  for (int i = 0; i < 4; ++i) {
    int r = threadIdx.y + i * 8;
    WT[(long)(bx * 32 + r) * 1024 + nx] = f2bf(tile[threadIdx.x][r]);
  }
}

// ---------------- V columns of QKV -> Vt[bh][hd][s_perm] ----------------
__global__ __launch_bounds__(256) void transpose_v(const unsigned short* __restrict__ QKV,
                                                   unsigned short* __restrict__ Vt) {
  __shared__ alignas(16) unsigned short tile[64][74];
  const int bid = blockIdx.x;
  const int st = bid & 31, bh = bid >> 5;
  const int b = bh >> 4, h = bh & 15;
  const int t = threadIdx.x;
  const int r = t >> 2, c16 = (t & 3) * 16;
  const unsigned short* src =
      QKV + ((long)(b * 2048 + st * 64 + r)) * 3072 + 2048 + h * 64 + c16;
  uint4v v0 = *(const uint4v*)src;
  uint4v v1 = *(const uint4v*)(src + 8);
  unsigned* dst32 = (unsigned*)&tile[r][c16];
  dst32[0] = v0[0]; dst32[1] = v0[1]; dst32[2] = v0[2]; dst32[3] = v0[3];
  dst32[4] = v1[0]; dst32[5] = v1[1]; dst32[6] = v1[2]; dst32[7] = v1[3];
  __syncthreads();
  const int lw = t & 63, w = t >> 6;
  const int vp = (lw & 32) | (((lw >> 2) & 3) << 3) | (((lw >> 4) & 1) << 2) | (lw & 3);
#pragma unroll
  for (int k = 0; k < 16; ++k) {
    int hd = w * 16 + k;
    Vt[((long)(bh * 64 + hd)) * 2048 + st * 64 + vp] = tile[lw][hd];
  }
}

// ---------------- GEMM v2: 8-wave, BK=64, counted-vmcnt dbuf, T2 swizzle ----
// C[M][N] = A[M][K] * BT[N][K]^T.  512 threads = 8 waves (WM x WN).
// LDS [row][8 slots of 16B], slot stored swizzled: lds_slot = g_slot ^ (row&7).
template <int BM, int BN, int WM, int WN, int FP32OUT>
__global__ __launch_bounds__(512, 2) void gemm_bt2(const unsigned short* __restrict__ A,
                                                   const unsigned short* __restrict__ BT,
                                                   unsigned short* __restrict__ Cb,
                                                   float* __restrict__ Cf,
                                                   const float* __restrict__ bias,
                                                   int M, int N, int K) {
  constexpr int MR = BM / WM / 16;
  constexpr int NR = BN / WN / 16;
  constexpr int L = BM / 64 + BN / 64;  // gloads per thread per K-tile
  __shared__ alignas(16) unsigned short As[2][BM * 64];
  __shared__ alignas(16) unsigned short Bs[2][BN * 64];

  const int nbn = N / BN;
  const int tmg = (M / BM) / 8;  // tm-rows per XCD (requires (M/BM)%8==0)
  const int bid = blockIdx.x;
  const int c = bid >> 3, x = bid & 7;
  const int tm = x * tmg + c / nbn, tn = c % nbn;

  const int t = threadIdx.x, l = t & 63, wid = t >> 6;
  const int wm = wid / WN, wn = wid % WN;
  const int lr = l & 15, lg = l >> 4;
  const int abase = wm * (MR * 16);
  const int bbase = wn * (NR * 16);

  f32x4 acc[MR][NR] = {};

  // staging source (inverse-swizzled global address; linear LDS dest)
  const int srow8 = l >> 3;
  const int sslot = (l & 7) ^ srow8;
  const unsigned short* Ab = A + (long)(tm * BM + wid * 8 + srow8) * K + sslot * 8;
  const unsigned short* Bb = BT + (long)(tn * BN + wid * 8 + srow8) * K + sslot * 8;

  auto STG = [&](int buf, int kt) {
    const int k0 = kt * 64;
#pragma unroll
    for (int ra = 0; ra < BM / 64; ++ra)
      gload16(Ab + (long)(ra * 64) * K + k0, &As[buf][(wid * 8 + ra * 64) * 64]);
#pragma unroll
    for (int rb = 0; rb < BN / 64; ++rb)
      gload16(Bb + (long)(rb * 64) * K + k0, &Bs[buf][(wid * 8 + rb * 64) * 64]);
  };

  const int NT = K >> 6;
  STG(0, 0);
  STG(1, 1);

  const int off0 = (lg ^ (lr & 7)) << 3;  // element offset of k-slice 0 slot

  for (int tt = 0; tt < NT; ++tt) {
    if (tt == NT - 1)
      asm volatile("s_waitcnt vmcnt(0)" ::: "memory");
    else if constexpr (L == 8)
      asm volatile("s_waitcnt vmcnt(8)" ::: "memory");
    else
      asm volatile("s_waitcnt vmcnt(6)" ::: "memory");
    asm volatile("s_barrier" ::: "memory");

    const unsigned short* Ac = &As[tt & 1][0];
    const unsigned short* Bc = &Bs[tt & 1][0];

    bf16x8 bfr[NR][2];
#pragma unroll
    for (int n = 0; n < NR; ++n) {
      const unsigned short* bp = Bc + (bbase + n * 16 + lr) * 64;
#pragma unroll
      for (int ks = 0; ks < 2; ++ks)
        bfr[n][ks] = *(const bf16x8*)(bp + (off0 ^ (ks << 5)));
    }
#pragma unroll
    for (int mh = 0; mh < 2; ++mh) {
      bf16x8 af[MR / 2][2];
#pragma unroll
      for (int mi = 0; mi < MR / 2; ++mi) {
        const unsigned short* ap = Ac + (abase + (mh * (MR / 2) + mi) * 16 + lr) * 64;
#pragma unroll
        for (int ks = 0; ks < 2; ++ks)
          af[mi][ks] = *(const bf16x8*)(ap + (off0 ^ (ks << 5)));
      }
      __builtin_amdgcn_s_setprio(1);
#pragma unroll
      for (int mi = 0; mi < MR / 2; ++mi)
#pragma unroll
        for (int n = 0; n < NR; ++n)
#pragma unroll
          for (int ks = 0; ks < 2; ++ks)
            acc[mh * (MR / 2) + mi][n] =
                MFMA16(af[mi][ks], bfr[n][ks], acc[mh * (MR / 2) + mi][n], 0, 0, 0);
      __builtin_amdgcn_s_setprio(0);
    }

    asm volatile("s_waitcnt lgkmcnt(0)" ::: "memory");
    asm volatile("s_barrier" ::: "memory");
    if (tt + 2 < NT) STG(tt & 1, tt + 2);
  }

  // epilogue
  const long crow = (long)tm * BM + abase;
  const int ccol = tn * BN + bbase;
#pragma unroll
  for (int m = 0; m < MR; ++m)
#pragma unroll
    for (int n = 0; n < NR; ++n)
#pragma unroll
      for (int r = 0; r < 4; ++r) {
        long row = crow + m * 16 + lg * 4 + r;
        int col = ccol + n * 16 + lr;
        if (FP32OUT)
          Cf[row * N + col] = acc[m][n][r] + bias[col];
        else
          Cb[row * N + col] = f2bf(acc[m][n][r]);
      }
}

// ---------------- Flash attention tile body ----------------
template <int TWO>
__device__ __forceinline__ void attn_tile(
    const unsigned short* __restrict__ Kc, const unsigned short* __restrict__ Vc,
    int lr, int lg, bool mask0, bool mask1, int kv0, int q0row, int q1row,
    const bf16x8 (&qf)[2][2], f32x4 (&cacc)[2][4], float (&m_r)[2], float (&l_r)[2]) {
  constexpr int S0 = TWO ? 0 : 1;
  f32x4 p[2][4];
#pragma unroll
  for (int s = S0; s < 2; ++s)
#pragma unroll
    for (int g = 0; g < 4; ++g) p[s][g] = f32x4{0.f, 0.f, 0.f, 0.f};

  __builtin_amdgcn_s_setprio(1);
#pragma unroll
  for (int g = 0; g < 4; ++g) {
    const int key = g * 16 + lr;
    const int swz = (key & 7) << 3;
#pragma unroll
    for (int c = 0; c < 2; ++c) {
      bf16x8 kf = *(const bf16x8*)(Kc + key * 64 + ((c * 32 + lg * 8) ^ swz));
#pragma unroll
      for (int s = S0; s < 2; ++s)
        p[s][g] = MFMA16(kf, qf[s][c], p[s][g], 0, 0, 0);
    }
  }
  __builtin_amdgcn_s_setprio(0);

  if (TWO && mask0) {
#pragma unroll
    for (int g = 0; g < 4; ++g)
#pragma unroll
      for (int r = 0; r < 4; ++r)
        if (kv0 + g * 16 + lg * 4 + r > q0row) p[0][g][r] = -1e30f;
  }
  if (mask1) {
#pragma unroll
    for (int g = 0; g < 4; ++g)
#pragma unroll
      for (int r = 0; r < 4; ++r)
        if (kv0 + g * 16 + lg * 4 + r > q1row) p[1][g][r] = -1e30f;
  }

  unsigned pk[2][4][2];
#pragma unroll
  for (int s = S0; s < 2; ++s) {
    float mloc = p[s][0][0];
#pragma unroll
    for (int g = 0; g < 4; ++g)
#pragma unroll
      for (int r = 0; r < 4; ++r) mloc = fmaxf(mloc, p[s][g][r]);
    mloc = fmaxf(mloc, __shfl_xor(mloc, 16));
    mloc = fmaxf(mloc, __shfl_xor(mloc, 32));
    const bool defer = __all(mloc <= m_r[s] + 44.0f);
    const float mn = defer ? m_r[s] : fmaxf(m_r[s], mloc);
    const float nmc = -mn * SM_C;
    float rs = 0.f;
#pragma unroll
    for (int g = 0; g < 4; ++g)
#pragma unroll
      for (int r = 0; r < 4; ++r) {
        float e = __builtin_amdgcn_exp2f(__builtin_fmaf(p[s][g][r], SM_C, nmc));
        p[s][g][r] = e;
        rs += e;
      }
    rs += __shfl_xor(rs, 16);
    rs += __shfl_xor(rs, 32);
    if (defer) {
      l_r[s] += rs;
    } else {
      float alpha = __builtin_amdgcn_exp2f((m_r[s] - mn) * SM_C);
      l_r[s] = l_r[s] * alpha + rs;
      m_r[s] = mn;
      float alq[4];
#pragma unroll
      for (int r = 0; r < 4; ++r) alq[r] = __shfl(alpha, lg * 20 + r);
#pragma unroll
      for (int n = 0; n < 4; ++n)
#pragma unroll
        for (int r = 0; r < 4; ++r) cacc[s][n][r] *= alq[r];
    }
#pragma unroll
    for (int g = 0; g < 4; ++g) {
      pk[s][g][0] = cvtpk(p[s][g][0], p[s][g][1]);
      pk[s][g][1] = cvtpk(p[s][g][2], p[s][g][3]);
    }
  }

#pragma unroll
  for (int sl = 0; sl < 2; ++sl) {
    bf16x8 vf[4];
#pragma unroll
    for (int n = 0; n < 4; ++n) {
      const int hd = n * 16 + lr;
      vf[n] = *(const bf16x8*)(Vc + hd * 64 + ((sl * 32 + lg * 8) ^ ((hd & 7) << 3)));
    }
    __builtin_amdgcn_s_setprio(1);
#pragma unroll
    for (int s = S0; s < 2; ++s) {
      uint4v pw = {pk[s][2 * sl][0], pk[s][2 * sl][1], pk[s][2 * sl + 1][0], pk[s][2 * sl + 1][1]};
      bf16x8 pa = __builtin_bit_cast(bf16x8, pw);
#pragma unroll
      for (int n = 0; n < 4; ++n)
        cacc[s][n] = MFMA16(pa, vf[n], cacc[s][n], 0, 0, 0);
    }
    __builtin_amdgcn_s_setprio(0);
  }
}

// ---------------- Flash attention (paired causal strips) ----------------
__global__ __launch_bounds__(256, 4) void flash_attn(const unsigned short* __restrict__ QKV,
                                                     const unsigned short* __restrict__ Vt,
                                                     unsigned short* __restrict__ Ctx) {
  __shared__ alignas(16) unsigned short Ks[2][64 * 64];
  __shared__ alignas(16) unsigned short Vs[2][64 * 64];
  const int bid = blockIdx.x;
  const int qt = bid >> 6;
  const int bh = bid & 63;
  const int b = bh >> 4, h = bh & 15;
  const int t = threadIdx.x, l = t & 63, w = t >> 6;
  const int lr = l & 15, lg = l >> 4;
  const long rowbase = (long)b * 2048;
  const int colbase = h * 64;
  const int q0 = qt * 64 + w * 16;
  const int q1 = (31 - qt) * 64 + w * 16;
  const int q0row = q0 + lr, q1row = q1 + lr;
  const int nkv = 32 - qt;

  bf16x8 qf[2][2];
#pragma unroll
  for (int c = 0; c < 2; ++c) {
    qf[0][c] = *(const bf16x8*)(QKV + (rowbase + q0 + lr) * 3072 + colbase + c * 32 + lg * 8);
    qf[1][c] = *(const bf16x8*)(QKV + (rowbase + q1 + lr) * 3072 + colbase + c * 32 + lg * 8);
  }

  f32x4 cacc[2][4];
  float m_r[2], l_r[2];
#pragma unroll
  for (int s = 0; s < 2; ++s) {
    m_r[s] = -1e30f;
    l_r[s] = 0.f;
#pragma unroll
    for (int n = 0; n < 4; ++n) cacc[s][n] = f32x4{0.f, 0.f, 0.f, 0.f};
  }

  const int srow = w * 16 + (l >> 3);
  const int scol = (l & 7) * 8;
  const int kswz = scol ^ ((srow & 7) << 3);
  const unsigned short* kp = QKV + (rowbase + srow) * 3072 + 1024 + colbase + kswz;
  const unsigned short* vp = Vt + ((long)(bh * 64 + srow)) * 2048 + kswz;
  unsigned short* ksd0 = &Ks[0][(w * 16) * 64];
  unsigned short* vsd0 = &Vs[0][(w * 16) * 64];

#define STAGE(buf)                                    \
  do {                                                \
    gload16(kp, ksd0 + (buf) * 4096);                 \
    gload16(kp + 8 * 3072, ksd0 + (buf) * 4096 + 512);\
    gload16(vp, vsd0 + (buf) * 4096);                 \
    gload16(vp + 8 * 2048, vsd0 + (buf) * 4096 + 512);\
    kp += 64 * 3072;                                  \
    vp += 64;                                         \
  } while (0)

  STAGE(0);
  __syncthreads();

  int j = 0;
  for (; j <= qt; ++j) {
    const int cur = j & 1;
    if (j + 1 < nkv) STAGE(cur ^ 1);
    attn_tile<1>(Ks[cur], Vs[cur], lr, lg, j == qt, false, j * 64, q0row, q1row,
                 qf, cacc, m_r, l_r);
    __syncthreads();
  }
  for (; j < nkv; ++j) {
    const int cur = j & 1;
    if (j + 1 < nkv) STAGE(cur ^ 1);
    attn_tile<0>(Ks[cur], Vs[cur], lr, lg, false, j == nkv - 1, j * 64, q0row, q1row,
                 qf, cacc, m_r, l_r);
    __syncthreads();
  }
#undef STAGE

#pragma unroll
  for (int s = 0; s < 2; ++s) {
    float invl = 1.f / l_r[s];
    float ilq[4];
#pragma unroll
    for (int r = 0; r < 4; ++r) ilq[r] = __shfl(invl, lg * 20 + r);
    const int qs = (s == 0) ? q0 : q1;
#pragma unroll
    for (int n = 0; n < 4; ++n)
#pragma unroll
      for (int r = 0; r < 4; ++r) {
        long row = rowbase + qs + lg * 4 + r;
        Ctx[row * 1024 + colbase + n * 16 + lr] = f2bf(cacc[s][n][r] * ilq[r]);
      }
  }
}

extern "C" void kernel_launch(void* const* d_in, const int* in_sizes, int n_in,
                              void* d_out, int out_size, void* d_ws, size_t ws_size,
                              hipStream_t stream) {
  (void)in_sizes; (void)n_in; (void)out_size; (void)ws_size;
  const float* x  = (const float*)d_in[0];
  const float* Wq = (const float*)d_in[1];
  const float* Wk = (const float*)d_in[2];
  const float* Wv = (const float*)d_in[3];
  const float* Wo = (const float*)d_in[4];
  const float* bo = (const float*)d_in[5];
  float* out = (float*)d_out;

  unsigned short* ws = (unsigned short*)d_ws;
  unsigned short* xb  = ws;                       // 8192*1024 (dead after QKV GEMM)
  unsigned short* Vt  = ws;                       // aliases xb: written after GEMM
  unsigned short* WqT = ws + 8388608;
  unsigned short* WkT = WqT + 1048576;
  unsigned short* WvT = WkT + 1048576;
  unsigned short* WoT = WvT + 1048576;
  unsigned short* QKV = WoT + 1048576;            // 8192*3072
  unsigned short* Ctx = QKV + 25165824;           // 8192*1024

  cvt_x<<<2048, 256, 0, stream>>>(x, xb, 8192 * 1024 / 4);

  dim3 tb(32, 8), tg(32, 32);
  transpose_w<<<tg, tb, 0, stream>>>(Wq, WqT);
  transpose_w<<<tg, tb, 0, stream>>>(Wk, WkT);
  transpose_w<<<tg, tb, 0, stream>>>(Wv, WvT);
  transpose_w<<<tg, tb, 0, stream>>>(Wo, WoT);

  // fused QKV projection: M=8192, N=3072, K=1024 (256x256 tiles, 384 blocks)
  gemm_bt2<256, 256, 2, 4, 0><<<384, 512, 0, stream>>>(xb, WqT, QKV, nullptr, nullptr,
                                                       8192, 3072, 1024);

  // V -> Vt[bh][hd][s_perm]  (xb dead; Vt aliases it)
  transpose_v<<<2048, 256, 0, stream>>>(QKV, Vt);

  // flash attention: 64 bh x 16 paired-strip blocks
  flash_attn<<<1024, 256, 0, stream>>>(QKV, Vt, Ctx);

  // output projection + bias: fp32 out (256x128 tiles, 256 blocks exact)
  gemm_bt2<256, 128, 4, 2, 1><<<256, 512, 0, stream>>>(Ctx, WoT, nullptr, out, bo,
                                                       8192, 1024, 1024);
}

// Round 6
// 173.484 us; speedup vs baseline: 2.5167x; 1.0152x over previous
//
#include <hip/hip_runtime.h>

typedef __attribute__((ext_vector_type(8))) short bf16x8;
typedef __attribute__((ext_vector_type(4))) float f32x4;
typedef __attribute__((ext_vector_type(4))) unsigned uint4v;

#define SM_C 0.18033688011112042f  // 0.125 * log2(e)
#define MFMA16 __builtin_amdgcn_mfma_f32_16x16x32_bf16

__device__ __forceinline__ unsigned short f2bf(float f) {
  unsigned u = __builtin_bit_cast(unsigned, f);
  u += 0x7fffu + ((u >> 16) & 1u);
  return (unsigned short)(u >> 16);
}

__device__ __forceinline__ unsigned cvtpk(float lo, float hi) {
  unsigned r;
  asm volatile("v_cvt_pk_bf16_f32 %0, %1, %2" : "=v"(r) : "v"(lo), "v"(hi));
  return r;
}

__device__ __forceinline__ void gload16(const void* g, void* lds) {
  __builtin_amdgcn_global_load_lds(
      (const __attribute__((address_space(1))) void*)g,
      (__attribute__((address_space(3))) void*)lds, 16, 0, 0);
}

// ---------------- x -> bf16 ----------------
__global__ __launch_bounds__(256) void cvt_x(const float* __restrict__ in,
                                             unsigned short* __restrict__ out,
                                             int n4) {
  int i = blockIdx.x * 256 + threadIdx.x;
  int stride = gridDim.x * 256;
  for (; i < n4; i += stride) {
    float4 v = ((const float4*)in)[i];
    unsigned short o0 = f2bf(v.x), o1 = f2bf(v.y), o2 = f2bf(v.z), o3 = f2bf(v.w);
    unsigned long long packed = (unsigned long long)o0 | ((unsigned long long)o1 << 16) |
                                ((unsigned long long)o2 << 32) | ((unsigned long long)o3 << 48);
    ((unsigned long long*)out)[i] = packed;
  }
}

// ---------------- W[K][N] f32 -> WT[N][K] bf16 ----------------
__global__ __launch_bounds__(256) void transpose_w(const float* __restrict__ W,
                                                   unsigned short* __restrict__ WT) {
  __shared__ float tile[32][33];
  int bx = blockIdx.x, by = blockIdx.y;
  int x = bx * 32 + threadIdx.x;
  for (int i = 0; i < 4; ++i) {
    int r = threadIdx.y + i * 8;
    tile[r][threadIdx.x] = W[(by * 32 + r) * 1024 + x];
  }
  __syncthreads();
  int nx = by * 32 + threadIdx.x;
  for (int i = 0; i < 4; ++i) {
    int r = threadIdx.y + i * 8;
    WT[(long)(bx * 32 + r) * 1024 + nx] = f2bf(tile[threadIdx.x][r]);
  }
}

// ---------------- V columns of QKV -> Vt[bh][hd][s_perm] ----------------
__global__ __launch_bounds__(256) void transpose_v(const unsigned short* __restrict__ QKV,
                                                   unsigned short* __restrict__ Vt) {
  __shared__ alignas(16) unsigned short tile[64][74];
  const int bid = blockIdx.x;
  const int st = bid & 31, bh = bid >> 5;
  const int b = bh >> 4, h = bh & 15;
  const int t = threadIdx.x;
  const int r = t >> 2, c16 = (t & 3) * 16;
  const unsigned short* src =
      QKV + ((long)(b * 2048 + st * 64 + r)) * 3072 + 2048 + h * 64 + c16;
  uint4v v0 = *(const uint4v*)src;
  uint4v v1 = *(const uint4v*)(src + 8);
  unsigned* dst32 = (unsigned*)&tile[r][c16];
  dst32[0] = v0[0]; dst32[1] = v0[1]; dst32[2] = v0[2]; dst32[3] = v0[3];
  dst32[4] = v1[0]; dst32[5] = v1[1]; dst32[6] = v1[2]; dst32[7] = v1[3];
  __syncthreads();
  const int lw = t & 63, w = t >> 6;
  const int vp = (lw & 32) | (((lw >> 2) & 3) << 3) | (((lw >> 4) & 1) << 2) | (lw & 3);
#pragma unroll
  for (int k = 0; k < 16; ++k) {
    int hd = w * 16 + k;
    Vt[((long)(bh * 64 + hd)) * 2048 + st * 64 + vp] = tile[lw][hd];
  }
}

// ---------------- GEMM v3: 8-wave 256xBN, BK=64, 4-phase interleave ---------
// C[M][N] = A[M][K] * BT[N][K]^T.  512 threads = 8 waves (2M x 4N).
// Per K-tile: 4 phases, each { 12 ds_read_b128 quadrant ; stage 2 quarter-
// tiles of K-tile t+1 ; 16 (or 8) MFMA in setprio ; barrier }, counted vmcnt
// at mid (4) and end (2) only — never 0 in steady state.
template <int BN, int FP32OUT>
__global__ __launch_bounds__(512, 1) void gemm8(const unsigned short* __restrict__ A,
                                                const unsigned short* __restrict__ BT,
                                                unsigned short* __restrict__ Cb,
                                                float* __restrict__ Cf,
                                                const float* __restrict__ bias,
                                                int M, int N, int K) {
  constexpr int NR = BN / 64;       // N-frags per wave (4 or 2)
  constexpr int NBQ = BN / 64;      // B quarters per K-tile
  constexpr int NH = NR / 2;        // B-frags per phase
  __shared__ alignas(16) unsigned short As[2][256 * 64];
  __shared__ alignas(16) unsigned short Bs[2][BN * 64];

  const int nbn = N / BN;
  const int tmg = (M / 256) / 8;    // XCD-bijective (requires (M/256)%8==0)
  const int bid = blockIdx.x;
  const int cc = bid >> 3, xc = bid & 7;
  const int tm = xc * tmg + cc / nbn, tn = cc % nbn;

  const int t = threadIdx.x, l = t & 63, wid = t >> 6;
  const int wm = wid >> 2, wn = wid & 3;
  const int lr = l & 15, lg = l >> 4;

  f32x4 acc[8][NR] = {};

  // staging geometry: thread t covers (row=t>>3, slot=t&7) of each 64-row
  // quarter; source pre-swizzled (slot ^ row&7), LDS dest linear (rule 21).
  const int srow = t >> 3;
  const int sslot = (t & 7) ^ (srow & 7);
  const unsigned short* Ag = A + (long)(tm * 256 + srow) * K + sslot * 8;
  const unsigned short* Bg = BT + (long)(tn * BN + srow) * K + sslot * 8;

#define STGA(buf, q, kt) gload16(Ag + (long)(q)*64 * K + (kt)*64, &As[buf][(q)*4096 + t * 8])
#define STGB(buf, q, kt) gload16(Bg + (long)(q)*64 * K + (kt)*64, &Bs[buf][(q)*4096 + t * 8])

  const int NT = K >> 6;
  // prologue: consumption-priority order; last two (A1,A3) may stay in flight
  if constexpr (NBQ == 4) {
    STGB(0, 0, 0); STGB(0, 1, 0); STGB(0, 2, 0); STGB(0, 3, 0);
    STGA(0, 0, 0); STGA(0, 2, 0); STGA(0, 1, 0); STGA(0, 3, 0);
  } else {
    STGB(0, 0, 0); STGB(0, 1, 0);
    STGA(0, 0, 0); STGA(0, 2, 0); STGA(0, 1, 0); STGA(0, 3, 0);
  }
  asm volatile("s_waitcnt vmcnt(2)" ::: "memory");
  asm volatile("s_barrier" ::: "memory");

  const int offk0 = ((0 + lg) ^ (lr & 7)) * 8;
  const int offk1 = ((4 + lg) ^ (lr & 7)) * 8;
  const int arow0 = (wm * 128 + lr) * 64;
  const int brow0 = (wn * (NR * 16) + lr) * 64;

#define DS_A(MH)                                                   \
  _Pragma("unroll") for (int m_ = 0; m_ < 4; ++m_) {               \
    const unsigned short* ap_ = Ac + arow0 + ((MH)*4 + m_) * 1024; \
    af[m_][0] = *(const bf16x8*)(ap_ + offk0);                     \
    af[m_][1] = *(const bf16x8*)(ap_ + offk1);                     \
  }
#define DS_B(NHI)                                                   \
  _Pragma("unroll") for (int n_ = 0; n_ < NH; ++n_) {               \
    const unsigned short* bp_ = Bc + brow0 + ((NHI)*NH + n_) * 1024;\
    bfr[n_][0] = *(const bf16x8*)(bp_ + offk0);                     \
    bfr[n_][1] = *(const bf16x8*)(bp_ + offk1);                     \
  }
#define MM(MH, NHI)                                                              \
  __builtin_amdgcn_s_setprio(1);                                                 \
  _Pragma("unroll") for (int m_ = 0; m_ < 4; ++m_)                               \
  _Pragma("unroll") for (int n_ = 0; n_ < NH; ++n_) {                            \
    acc[(MH)*4 + m_][(NHI)*NH + n_] =                                            \
        MFMA16(af[m_][0], bfr[n_][0], acc[(MH)*4 + m_][(NHI)*NH + n_], 0, 0, 0); \
    acc[(MH)*4 + m_][(NHI)*NH + n_] =                                            \
        MFMA16(af[m_][1], bfr[n_][1], acc[(MH)*4 + m_][(NHI)*NH + n_], 0, 0, 0); \
  }                                                                              \
  __builtin_amdgcn_s_setprio(0);

  for (int tt = 0; tt < NT; ++tt) {
    const unsigned short* Ac = As[tt & 1];
    const unsigned short* Bc = Bs[tt & 1];
    const int nb = (tt & 1) ^ 1;
    const int kt = tt + 1;
    const bool st = kt < NT;

    bf16x8 af[4][2];
    bf16x8 bfr[NH][2];

    // phase 0: quadrant (0,0)
    DS_A(0);
    DS_B(0);
    if (st) { STGB(nb, 0, kt); STGB(nb, 1, kt); }
    MM(0, 0);
    asm volatile("s_barrier" ::: "memory");

    // phase 1: quadrant (0,1)
    DS_B(1);
    if (st) {
      if constexpr (NBQ == 4) { STGB(nb, 2, kt); STGB(nb, 3, kt); }
      else { STGA(nb, 0, kt); STGA(nb, 2, kt); }
    }
    MM(0, 1);
    if (st) asm volatile("s_waitcnt vmcnt(4)" ::: "memory");
    else    asm volatile("s_waitcnt vmcnt(0)" ::: "memory");
    asm volatile("s_barrier" ::: "memory");

    // phase 2: quadrant (1,1)
    DS_A(1);
    if (st) {
      if constexpr (NBQ == 4) { STGA(nb, 0, kt); STGA(nb, 2, kt); }
      else { STGA(nb, 1, kt); STGA(nb, 3, kt); }
    }
    MM(1, 1);
    asm volatile("s_barrier" ::: "memory");

    // phase 3: quadrant (1,0)
    DS_B(0);
    if (st) {
      if constexpr (NBQ == 4) { STGA(nb, 1, kt); STGA(nb, 3, kt); }
    }
    MM(1, 0);
    if (st) asm volatile("s_waitcnt vmcnt(2)" ::: "memory");
    asm volatile("s_barrier" ::: "memory");
  }
#undef DS_A
#undef DS_B
#undef MM
#undef STGA
#undef STGB

  // epilogue
  const long crow = (long)tm * 256 + wm * 128;
  const int ccol = tn * BN + wn * (NR * 16);
#pragma unroll
  for (int m = 0; m < 8; ++m)
#pragma unroll
    for (int n = 0; n < NR; ++n)
#pragma unroll
      for (int r = 0; r < 4; ++r) {
        long row = crow + m * 16 + lg * 4 + r;
        int col = ccol + n * 16 + lr;
        if (FP32OUT)
          Cf[row * N + col] = acc[m][n][r] + bias[col];
        else
          Cb[row * N + col] = f2bf(acc[m][n][r]);
      }
}

// ---------------- Flash attention tile body ----------------
template <int TWO>
__device__ __forceinline__ void attn_tile(
    const unsigned short* __restrict__ Kc, const unsigned short* __restrict__ Vc,
    int lr, int lg, bool mask0, bool mask1, int kv0, int q0row, int q1row,
    const bf16x8 (&qf)[2][2], f32x4 (&cacc)[2][4], float (&m_r)[2], float (&l_r)[2]) {
  constexpr int S0 = TWO ? 0 : 1;
  f32x4 p[2][4];
#pragma unroll
  for (int s = S0; s < 2; ++s)
#pragma unroll
    for (int g = 0; g < 4; ++g) p[s][g] = f32x4{0.f, 0.f, 0.f, 0.f};

  __builtin_amdgcn_s_setprio(1);
#pragma unroll
  for (int g = 0; g < 4; ++g) {
    const int key = g * 16 + lr;
    const int swz = (key & 7) << 3;
#pragma unroll
    for (int c = 0; c < 2; ++c) {
      bf16x8 kf = *(const bf16x8*)(Kc + key * 64 + ((c * 32 + lg * 8) ^ swz));
#pragma unroll
      for (int s = S0; s < 2; ++s)
        p[s][g] = MFMA16(kf, qf[s][c], p[s][g], 0, 0, 0);
    }
  }
  __builtin_amdgcn_s_setprio(0);

  if (TWO && mask0) {
#pragma unroll
    for (int g = 0; g < 4; ++g)
#pragma unroll
      for (int r = 0; r < 4; ++r)
        if (kv0 + g * 16 + lg * 4 + r > q0row) p[0][g][r] = -1e30f;
  }
  if (mask1) {
#pragma unroll
    for (int g = 0; g < 4; ++g)
#pragma unroll
      for (int r = 0; r < 4; ++r)
        if (kv0 + g * 16 + lg * 4 + r > q1row) p[1][g][r] = -1e30f;
  }

  unsigned pk[2][4][2];
#pragma unroll
  for (int s = S0; s < 2; ++s) {
    float mloc = p[s][0][0];
#pragma unroll
    for (int g = 0; g < 4; ++g)
#pragma unroll
      for (int r = 0; r < 4; ++r) mloc = fmaxf(mloc, p[s][g][r]);
    mloc = fmaxf(mloc, __shfl_xor(mloc, 16));
    mloc = fmaxf(mloc, __shfl_xor(mloc, 32));
    const bool defer = __all(mloc <= m_r[s] + 44.0f);
    const float mn = defer ? m_r[s] : fmaxf(m_r[s], mloc);
    const float nmc = -mn * SM_C;
    float rs = 0.f;
#pragma unroll
    for (int g = 0; g < 4; ++g)
#pragma unroll
      for (int r = 0; r < 4; ++r) {
        float e = __builtin_amdgcn_exp2f(__builtin_fmaf(p[s][g][r], SM_C, nmc));
        p[s][g][r] = e;
        rs += e;
      }
    rs += __shfl_xor(rs, 16);
    rs += __shfl_xor(rs, 32);
    if (defer) {
      l_r[s] += rs;
    } else {
      float alpha = __builtin_amdgcn_exp2f((m_r[s] - mn) * SM_C);
      l_r[s] = l_r[s] * alpha + rs;
      m_r[s] = mn;
      float alq[4];
#pragma unroll
      for (int r = 0; r < 4; ++r) alq[r] = __shfl(alpha, lg * 20 + r);
#pragma unroll
      for (int n = 0; n < 4; ++n)
#pragma unroll
        for (int r = 0; r < 4; ++r) cacc[s][n][r] *= alq[r];
    }
#pragma unroll
    for (int g = 0; g < 4; ++g) {
      pk[s][g][0] = cvtpk(p[s][g][0], p[s][g][1]);
      pk[s][g][1] = cvtpk(p[s][g][2], p[s][g][3]);
    }
  }

#pragma unroll
  for (int sl = 0; sl < 2; ++sl) {
    bf16x8 vf[4];
#pragma unroll
    for (int n = 0; n < 4; ++n) {
      const int hd = n * 16 + lr;
      vf[n] = *(const bf16x8*)(Vc + hd * 64 + ((sl * 32 + lg * 8) ^ ((hd & 7) << 3)));
    }
    __builtin_amdgcn_s_setprio(1);
#pragma unroll
    for (int s = S0; s < 2; ++s) {
      uint4v pw = {pk[s][2 * sl][0], pk[s][2 * sl][1], pk[s][2 * sl + 1][0], pk[s][2 * sl + 1][1]};
      bf16x8 pa = __builtin_bit_cast(bf16x8, pw);
#pragma unroll
      for (int n = 0; n < 4; ++n)
        cacc[s][n] = MFMA16(pa, vf[n], cacc[s][n], 0, 0, 0);
    }
    __builtin_amdgcn_s_setprio(0);
  }
}

// ---------------- Flash attention (paired causal strips) ----------------
__global__ __launch_bounds__(256, 4) void flash_attn(const unsigned short* __restrict__ QKV,
                                                     const unsigned short* __restrict__ Vt,
                                                     unsigned short* __restrict__ Ctx) {
  __shared__ alignas(16) unsigned short Ks[2][64 * 64];
  __shared__ alignas(16) unsigned short Vs[2][64 * 64];
  const int bid = blockIdx.x;
  const int qt = bid >> 6;
  const int bh = bid & 63;
  const int b = bh >> 4, h = bh & 15;
  const int t = threadIdx.x, l = t & 63, w = t >> 6;
  const int lr = l & 15, lg = l >> 4;
  const long rowbase = (long)b * 2048;
  const int colbase = h * 64;
  const int q0 = qt * 64 + w * 16;
  const int q1 = (31 - qt) * 64 + w * 16;
  const int q0row = q0 + lr, q1row = q1 + lr;
  const int nkv = 32 - qt;

  bf16x8 qf[2][2];
#pragma unroll
  for (int c = 0; c < 2; ++c) {
    qf[0][c] = *(const bf16x8*)(QKV + (rowbase + q0 + lr) * 3072 + colbase + c * 32 + lg * 8);
    qf[1][c] = *(const bf16x8*)(QKV + (rowbase + q1 + lr) * 3072 + colbase + c * 32 + lg * 8);
  }

  f32x4 cacc[2][4];
  float m_r[2], l_r[2];
#pragma unroll
  for (int s = 0; s < 2; ++s) {
    m_r[s] = -1e30f;
    l_r[s] = 0.f;
#pragma unroll
    for (int n = 0; n < 4; ++n) cacc[s][n] = f32x4{0.f, 0.f, 0.f, 0.f};
  }

  const int srow = w * 16 + (l >> 3);
  const int scol = (l & 7) * 8;
  const int kswz = scol ^ ((srow & 7) << 3);
  const unsigned short* kp = QKV + (rowbase + srow) * 3072 + 1024 + colbase + kswz;
  const unsigned short* vp = Vt + ((long)(bh * 64 + srow)) * 2048 + kswz;
  unsigned short* ksd0 = &Ks[0][(w * 16) * 64];
  unsigned short* vsd0 = &Vs[0][(w * 16) * 64];

#define STAGE(buf)                                    \
  do {                                                \
    gload16(kp, ksd0 + (buf) * 4096);                 \
    gload16(kp + 8 * 3072, ksd0 + (buf) * 4096 + 512);\
    gload16(vp, vsd0 + (buf) * 4096);                 \
    gload16(vp + 8 * 2048, vsd0 + (buf) * 4096 + 512);\
    kp += 64 * 3072;                                  \
    vp += 64;                                         \
  } while (0)

  STAGE(0);
  __syncthreads();

  int j = 0;
  for (; j <= qt; ++j) {
    const int cur = j & 1;
    if (j + 1 < nkv) STAGE(cur ^ 1);
    attn_tile<1>(Ks[cur], Vs[cur], lr, lg, j == qt, false, j * 64, q0row, q1row,
                 qf, cacc, m_r, l_r);
    __syncthreads();
  }
  for (; j < nkv; ++j) {
    const int cur = j & 1;
    if (j + 1 < nkv) STAGE(cur ^ 1);
    attn_tile<0>(Ks[cur], Vs[cur], lr, lg, false, j == nkv - 1, j * 64, q0row, q1row,
                 qf, cacc, m_r, l_r);
    __syncthreads();
  }
#undef STAGE

#pragma unroll
  for (int s = 0; s < 2; ++s) {
    float invl = 1.f / l_r[s];
    float ilq[4];
#pragma unroll
    for (int r = 0; r < 4; ++r) ilq[r] = __shfl(invl, lg * 20 + r);
    const int qs = (s == 0) ? q0 : q1;
#pragma unroll
    for (int n = 0; n < 4; ++n)
#pragma unroll
      for (int r = 0; r < 4; ++r) {
        long row = rowbase + qs + lg * 4 + r;
        Ctx[row * 1024 + colbase + n * 16 + lr] = f2bf(cacc[s][n][r] * ilq[r]);
      }
  }
}

extern "C" void kernel_launch(void* const* d_in, const int* in_sizes, int n_in,
                              void* d_out, int out_size, void* d_ws, size_t ws_size,
                              hipStream_t stream) {
  (void)in_sizes; (void)n_in; (void)out_size; (void)ws_size;
  const float* x  = (const float*)d_in[0];
  const float* Wq = (const float*)d_in[1];
  const float* Wk = (const float*)d_in[2];
  const float* Wv = (const float*)d_in[3];
  const float* Wo = (const float*)d_in[4];
  const float* bo = (const float*)d_in[5];
  float* out = (float*)d_out;

  unsigned short* ws = (unsigned short*)d_ws;
  unsigned short* xb  = ws;                       // 8192*1024 (dead after QKV GEMM)
  unsigned short* Vt  = ws;                       // aliases xb: written after GEMM
  unsigned short* WqT = ws + 8388608;
  unsigned short* WkT = WqT + 1048576;
  unsigned short* WvT = WkT + 1048576;
  unsigned short* WoT = WvT + 1048576;
  unsigned short* QKV = WoT + 1048576;            // 8192*3072
  unsigned short* Ctx = QKV + 25165824;           // 8192*1024

  cvt_x<<<2048, 256, 0, stream>>>(x, xb, 8192 * 1024 / 4);

  dim3 tb(32, 8), tg(32, 32);
  transpose_w<<<tg, tb, 0, stream>>>(Wq, WqT);
  transpose_w<<<tg, tb, 0, stream>>>(Wk, WkT);
  transpose_w<<<tg, tb, 0, stream>>>(Wv, WvT);
  transpose_w<<<tg, tb, 0, stream>>>(Wo, WoT);

  // fused QKV projection: M=8192, N=3072, K=1024 (256x256 tiles, 384 blocks)
  gemm8<256, 0><<<384, 512, 0, stream>>>(xb, WqT, QKV, nullptr, nullptr,
                                         8192, 3072, 1024);

  // V -> Vt[bh][hd][s_perm]  (xb dead; Vt aliases it)
  transpose_v<<<2048, 256, 0, stream>>>(QKV, Vt);

  // flash attention: 64 bh x 16 paired-strip blocks
  flash_attn<<<1024, 256, 0, stream>>>(QKV, Vt, Ctx);

  // output projection + bias: fp32 out (256x128 tiles, 256 blocks exact)
  gemm8<128, 1><<<256, 512, 0, stream>>>(Ctx, WoT, nullptr, out, bo,
                                         8192, 1024, 1024);
}